// Round 8
// baseline (11030.711 us; speedup 1.0000x reference)
//
#include <hip/hip_runtime.h>
#include <math.h>

// LightingSpeechShield — B=1024, F=257, C=32; fp32 in/out.
// R7: passed at 1593 µs; k_layer was LDS-bandwidth-bound (every FMA read both
// operands per-element from LDS; 60KB LDS -> 2 blocks/CU). This round:
// weights register-cached from global/L2 (coalesced), activations read as
// wave-broadcast float4 rows, stride-36 LDS tiles (16B aligned), shuffle-LN
// fused with store. LDS 59.5->46.3KB (3 blocks/CU), barriers 6->4.

#define BB 1024
#define FF 257
#define BF (BB*FF)
#define TILE 64
#define NT 5
#define NBLK (BB*NT)       // 5120
#define NLAYER 4
#define SQ 36              // qs/ks/vs/ys row stride (36*4=144, 16B-aligned)

__device__ __forceinline__ float gelu_exact(float x){
    return 0.5f*x*(1.0f+erff(x*0.70710678118654752f));
}

__global__ __launch_bounds__(256) void k_zero(float* __restrict__ stats){
    stats[threadIdx.x]=0.0f;   // 256 = NLAYER*64
}

// ---------------- input projection: h = x(B,F,18) @ in_w(18,32) + in_b ----------------
__global__ __launch_bounds__(256) void k_inproj(const float* __restrict__ x,
        const float* __restrict__ in_w, const float* __restrict__ in_b,
        float* __restrict__ h)
{
    __shared__ float xs[TILE*18];
    int b = blockIdx.x / NT, t = blockIdx.x % NT, t0 = t*TILE;
    int tid = threadIdx.x;
    int nv = min(TILE, FF-t0);
    for (int i=tid;i<nv*18;i+=256) xs[i]=x[(size_t)(b*FF+t0)*18+i];
    __syncthreads();
    int co=tid&31, rq=tid>>5;
    float acc[8];
    float bias = in_b[co];
    #pragma unroll
    for (int k=0;k<8;k++) acc[k]=bias;
    for (int ci=0;ci<18;ci++){
        float w = in_w[ci*32+co];              // coalesced, L2-resident
        #pragma unroll
        for (int k=0;k<8;k++){
            int r=rq*8+k;
            acc[k]=fmaf(xs[r*18+ci], w, acc[k]);   // broadcast read
        }
    }
    #pragma unroll
    for (int k=0;k<8;k++){
        int r=rq*8+k;
        if (r<nv) h[(size_t)(b*FF+t0+r)*32+co]=acc[k];
    }
}

// ---------------- conv (recompute, register-blocked) -> BN partial sums ----------------
__global__ __launch_bounds__(256) void k_convstats(const float* __restrict__ h,
        const float* __restrict__ conv_w, int layer, float* __restrict__ partials)
{
    __shared__ float hs[66*32];      // rows f = t0-1 .. t0+64
    __shared__ float ps[8][32];
    __shared__ float pq[8][32];
    int b=blockIdx.x/NT, t=blockIdx.x%NT, t0=t*TILE, tid=threadIdx.x;
    for (int i4=tid;i4<66*8;i4+=256){
        int r=i4>>3, f=t0-1+r;
        float4 v=make_float4(0.f,0.f,0.f,0.f);
        if (f>=0 && f<FF) v=*(const float4*)(h+(size_t)(b*FF+f)*32+(i4&7)*4);
        *(float4*)&hs[r*32+(i4&7)*4]=v;
    }
    __syncthreads();
    int co=tid&31, rq=tid>>5;
    float acc[8];
    #pragma unroll
    for (int k=0;k<8;k++) acc[k]=0.f;
    const float* wl = conv_w + layer*3072;
    for (int wi=0;wi<3;wi++){
        #pragma unroll
        for (int c4=0;c4<8;c4++){
            float w0=wl[(wi*32+c4*4+0)*32+co];
            float w1=wl[(wi*32+c4*4+1)*32+co];
            float w2=wl[(wi*32+c4*4+2)*32+co];
            float w3=wl[(wi*32+c4*4+3)*32+co];
            #pragma unroll
            for (int k=0;k<8;k++){
                float4 hv=*(const float4*)&hs[(rq*8+k+wi)*32+c4*4];  // broadcast
                acc[k]=fmaf(hv.x,w0,fmaf(hv.y,w1,fmaf(hv.z,w2,fmaf(hv.w,w3,acc[k]))));
            }
        }
    }
    float ssum=0.f, ssq=0.f;
    #pragma unroll
    for (int k=0;k<8;k++){
        int f=t0+rq*8+k;
        if (f<FF){ ssum+=acc[k]; ssq+=acc[k]*acc[k]; }
    }
    ps[rq][co]=ssum; pq[rq][co]=ssq;
    __syncthreads();
    if (tid<32){
        float s=0.f;
        #pragma unroll
        for(int q=0;q<8;q++) s+=ps[q][tid];
        partials[blockIdx.x*64+tid]=s;
    } else if (tid<64){
        int cc=tid-32;
        float s=0.f;
        #pragma unroll
        for(int q=0;q<8;q++) s+=pq[q][cc];
        partials[blockIdx.x*64+tid]=s;
    }
}

// ---------------- reduce partials -> stats[64] (sum | sumsq) ----------------
__global__ __launch_bounds__(256) void k_reduce(const float* __restrict__ partials,
        float* __restrict__ stats)
{
    __shared__ float sm[4][64];
    int tid=threadIdx.x, col=tid&63, rq=tid>>6;
    int r0=blockIdx.x*80;
    float s=0.f;
    for (int k=rq;k<80;k+=4) s += partials[(r0+k)*64+col];
    sm[rq][col]=s;
    __syncthreads();
    if (tid<64){
        float v=sm[0][tid]+sm[1][tid]+sm[2][tid]+sm[3][tid];
        atomicAdd(&stats[tid], v);
    }
}

// ---------------- fused layer ----------------
__global__ __launch_bounds__(256,3) void k_layer(const float* __restrict__ h,
        float* __restrict__ hn, const float* __restrict__ stats,
        const float* __restrict__ conv_w, const float* __restrict__ bn_g,
        const float* __restrict__ bn_b, const float* __restrict__ qkv_w,
        const float* __restrict__ proj_w, const float* __restrict__ proj_b,
        const float* __restrict__ ln_g, const float* __restrict__ ln_b, int layer)
{
    __shared__ float hs[67*32];            // rows f = t0-1 .. t0+65
    __shared__ float qs[66*SQ];            // becomes attn output in-place
    __shared__ float ks[66*SQ];
    __shared__ float vs[66*SQ];
    __shared__ float ys[64*SQ];

    int b=blockIdx.x/NT, t=blockIdx.x%NT, t0=t*TILE, tid=threadIdx.x;
    // stage hs (float4, coalesced)
    for (int i4=tid;i4<67*8;i4+=256){
        int r=i4>>3, f=t0-1+r;
        float4 v=make_float4(0.f,0.f,0.f,0.f);
        if (f>=0 && f<FF) v=*(const float4*)(h+(size_t)(b*FF+f)*32+(i4&7)*4);
        *(float4*)&hs[r*32+(i4&7)*4]=v;
    }
    __syncthreads();

    // ---- phase A (tid<192): qkv, thread owns one output column, 33 rows ----
    if (tid<192){
        int j=tid%96, g=tid/96;
        float qw[32];
        #pragma unroll
        for (int ci=0;ci<32;ci++) qw[ci]=qkv_w[layer*3072+ci*96+j];   // coalesced
        float* dst; int col;
        if (j<32){ dst=qs; col=j; } else if (j<64){ dst=ks; col=j-32; } else { dst=vs; col=j-64; }
        for (int rr=0;rr<33;rr++){
            int r=g*33+rr;
            if (t0+r<FF){
                float acc=0.f;
                #pragma unroll
                for (int c4=0;c4<8;c4++){
                    float4 hv=*(const float4*)&hs[(r+1)*32+c4*4];    // broadcast
                    acc=fmaf(hv.x,qw[c4*4+0],acc);
                    acc=fmaf(hv.y,qw[c4*4+1],acc);
                    acc=fmaf(hv.z,qw[c4*4+2],acc);
                    acc=fmaf(hv.w,qw[c4*4+3],acc);
                }
                dst[r*SQ+col]=acc;
            }
        }
    }
    // ---- phase B (all): conv + BN + gelu -> ys ----
    int co=tid&31, rq=tid>>5;
    {
        float mu  = stats[co]*(1.0f/(float)BF);
        float var = stats[32+co]*(1.0f/(float)BF) - mu*mu;
        float rs  = rsqrtf(fmaxf(var,0.f)+1e-5f);
        float g   = bn_g[layer*32+co];
        float scv = g*rs;
        float shv = bn_b[layer*32+co] - mu*g*rs;
        float acc[8];
        #pragma unroll
        for (int k=0;k<8;k++) acc[k]=0.f;
        const float* wl = conv_w + layer*3072;
        for (int wi=0;wi<3;wi++){
            #pragma unroll
            for (int c4=0;c4<8;c4++){
                float w0=wl[(wi*32+c4*4+0)*32+co];
                float w1=wl[(wi*32+c4*4+1)*32+co];
                float w2=wl[(wi*32+c4*4+2)*32+co];
                float w3=wl[(wi*32+c4*4+3)*32+co];
                #pragma unroll
                for (int k=0;k<8;k++){
                    float4 hv=*(const float4*)&hs[(rq*8+k+wi)*32+c4*4];
                    acc[k]=fmaf(hv.x,w0,fmaf(hv.y,w1,fmaf(hv.z,w2,fmaf(hv.w,w3,acc[k]))));
                }
            }
        }
        #pragma unroll
        for (int k=0;k<8;k++){
            int r=rq*8+k;
            if (t0+r<FF) ys[r*SQ+co]=gelu_exact(fmaf(acc[k],scv,shv));
        }
    }
    __syncthreads();

    // ---- phase C: banded attention (qs in-place) ----
    {
        int r=tid>>2, hh=tid&3, f=t0+r;
        if (f<FF){
            int base=hh*8;
            float4 qa=*(const float4*)&qs[r*SQ+base];
            float4 qb=*(const float4*)&qs[r*SQ+base+4];
            float s0, s1=-1e30f, s2=-1e30f;
            {
                float4 ka=*(const float4*)&ks[r*SQ+base];
                float4 kb=*(const float4*)&ks[r*SQ+base+4];
                s0=(qa.x*ka.x+qa.y*ka.y+qa.z*ka.z+qa.w*ka.w
                   +qb.x*kb.x+qb.y*kb.y+qb.z*kb.z+qb.w*kb.w)*0.35355339059327373f;
            }
            if (f+1<FF){
                float4 ka=*(const float4*)&ks[(r+1)*SQ+base];
                float4 kb=*(const float4*)&ks[(r+1)*SQ+base+4];
                s1=(qa.x*ka.x+qa.y*ka.y+qa.z*ka.z+qa.w*ka.w
                   +qb.x*kb.x+qb.y*kb.y+qb.z*kb.z+qb.w*kb.w)*0.35355339059327373f;
            }
            if (f+2<FF){
                float4 ka=*(const float4*)&ks[(r+2)*SQ+base];
                float4 kb=*(const float4*)&ks[(r+2)*SQ+base+4];
                s2=(qa.x*ka.x+qa.y*ka.y+qa.z*ka.z+qa.w*ka.w
                   +qb.x*kb.x+qb.y*kb.y+qb.z*kb.z+qb.w*kb.w)*0.35355339059327373f;
            }
            float mx=fmaxf(s0,fmaxf(s1,s2));
            float e0=expf(s0-mx);
            float e1=(f+1<FF)?expf(s1-mx):0.f;
            float e2=(f+2<FF)?expf(s2-mx):0.f;
            float inv=1.0f/(e0+e1+e2);
            float4 oa, ob;
            {
                float4 va=*(const float4*)&vs[r*SQ+base];
                float4 vb=*(const float4*)&vs[r*SQ+base+4];
                oa.x=e0*va.x; oa.y=e0*va.y; oa.z=e0*va.z; oa.w=e0*va.w;
                ob.x=e0*vb.x; ob.y=e0*vb.y; ob.z=e0*vb.z; ob.w=e0*vb.w;
            }
            if (f+1<FF){
                float4 va=*(const float4*)&vs[(r+1)*SQ+base];
                float4 vb=*(const float4*)&vs[(r+1)*SQ+base+4];
                oa.x=fmaf(e1,va.x,oa.x); oa.y=fmaf(e1,va.y,oa.y);
                oa.z=fmaf(e1,va.z,oa.z); oa.w=fmaf(e1,va.w,oa.w);
                ob.x=fmaf(e1,vb.x,ob.x); ob.y=fmaf(e1,vb.y,ob.y);
                ob.z=fmaf(e1,vb.z,ob.z); ob.w=fmaf(e1,vb.w,ob.w);
            }
            if (f+2<FF){
                float4 va=*(const float4*)&vs[(r+2)*SQ+base];
                float4 vb=*(const float4*)&vs[(r+2)*SQ+base+4];
                oa.x=fmaf(e2,va.x,oa.x); oa.y=fmaf(e2,va.y,oa.y);
                oa.z=fmaf(e2,va.z,oa.z); oa.w=fmaf(e2,va.w,oa.w);
                ob.x=fmaf(e2,vb.x,ob.x); ob.y=fmaf(e2,vb.y,ob.y);
                ob.z=fmaf(e2,vb.z,ob.z); ob.w=fmaf(e2,vb.w,ob.w);
            }
            oa.x*=inv; oa.y*=inv; oa.z*=inv; oa.w*=inv;
            ob.x*=inv; ob.y*=inv; ob.z*=inv; ob.w*=inv;
            *(float4*)&qs[r*SQ+base]=oa;
            *(float4*)&qs[r*SQ+base+4]=ob;
        }
    }
    __syncthreads();

    // ---- phase D: proj + residual into ys (same (co,rq) rows as B) ----
    {
        float pbv = proj_b[layer*32+co];
        float dacc[8];
        #pragma unroll
        for (int k=0;k<8;k++) dacc[k]=pbv;
        const float* pwl = proj_w + layer*1024;
        #pragma unroll
        for (int c4=0;c4<8;c4++){
            float w0=pwl[(c4*4+0)*32+co];
            float w1=pwl[(c4*4+1)*32+co];
            float w2=pwl[(c4*4+2)*32+co];
            float w3=pwl[(c4*4+3)*32+co];
            #pragma unroll
            for (int k=0;k<8;k++){
                float4 qv=*(const float4*)&qs[(rq*8+k)*SQ+c4*4];   // broadcast
                dacc[k]=fmaf(qv.x,w0,fmaf(qv.y,w1,fmaf(qv.z,w2,fmaf(qv.w,w3,dacc[k]))));
            }
        }
        #pragma unroll
        for (int k=0;k<8;k++){
            int r=rq*8+k;
            if (t0+r<FF) ys[r*SQ+co]+=dacc[k];
        }
    }
    __syncthreads();

    // ---- phase E+F: LayerNorm via shuffles + fused coalesced store ----
    {
        int r=tid>>2, q=tid&3, f=t0+r;
        if (f<FF){
            float4 a0=*(const float4*)&ys[r*SQ+q*8];
            float4 a1=*(const float4*)&ys[r*SQ+q*8+4];
            float s=a0.x+a0.y+a0.z+a0.w+a1.x+a1.y+a1.z+a1.w;
            s+=__shfl_xor(s,1); s+=__shfl_xor(s,2);
            float m=s*(1.0f/32.0f);
            float d, v=0.f;
            d=a0.x-m; v=fmaf(d,d,v); d=a0.y-m; v=fmaf(d,d,v);
            d=a0.z-m; v=fmaf(d,d,v); d=a0.w-m; v=fmaf(d,d,v);
            d=a1.x-m; v=fmaf(d,d,v); d=a1.y-m; v=fmaf(d,d,v);
            d=a1.z-m; v=fmaf(d,d,v); d=a1.w-m; v=fmaf(d,d,v);
            v+=__shfl_xor(v,1); v+=__shfl_xor(v,2);
            float rsd=rsqrtf(fmaxf(v,0.f)*(1.0f/32.0f)+1e-5f);
            float4 g0=*(const float4*)&ln_g[layer*32+q*8];
            float4 g1=*(const float4*)&ln_g[layer*32+q*8+4];
            float4 b0=*(const float4*)&ln_b[layer*32+q*8];
            float4 b1=*(const float4*)&ln_b[layer*32+q*8+4];
            float4 o0, o1;
            o0.x=(a0.x-m)*rsd*g0.x+b0.x; o0.y=(a0.y-m)*rsd*g0.y+b0.y;
            o0.z=(a0.z-m)*rsd*g0.z+b0.z; o0.w=(a0.w-m)*rsd*g0.w+b0.w;
            o1.x=(a1.x-m)*rsd*g1.x+b1.x; o1.y=(a1.y-m)*rsd*g1.y+b1.y;
            o1.z=(a1.z-m)*rsd*g1.z+b1.z; o1.w=(a1.w-m)*rsd*g1.w+b1.w;
            *(float4*)(hn+(size_t)(b*FF+f)*32+q*8)=o0;
            *(float4*)(hn+(size_t)(b*FF+f)*32+q*8+4)=o1;
        }
    }
}

// ---------------- head: sigmoid(gelu(h@h1+b1)@h2+b2) ----------------
__global__ __launch_bounds__(256) void k_head(const float* __restrict__ h,
        const float* __restrict__ h1_w, const float* __restrict__ h1_b,
        const float* __restrict__ h2_w, const float* __restrict__ h2_b,
        float* __restrict__ out)
{
    __shared__ float hs[256*SQ];
    __shared__ float w1t[16*32];     // transposed h1_w
    int tid=threadIdx.x;
    int r0=blockIdx.x*256;           // BF == 1028*256 exactly
    for (int i4=tid;i4<256*8;i4+=256){
        float4 v=*(const float4*)(h+(size_t)r0*32+i4*4);
        *(float4*)&hs[(i4>>3)*SQ+(i4&7)*4]=v;
    }
    for (int i=tid;i<512;i+=256) w1t[i]=h1_w[(i&31)*16+(i>>5)];
    __syncthreads();
    float accj[16];
    #pragma unroll
    for (int j=0;j<16;j++) accj[j]=h1_b[j];
    #pragma unroll
    for (int c4=0;c4<8;c4++){
        float4 hv=*(const float4*)&hs[tid*SQ+c4*4];
        #pragma unroll
        for (int j=0;j<16;j++){
            float4 wv=*(const float4*)&w1t[j*32+c4*4];    // broadcast
            accj[j]=fmaf(hv.x,wv.x,fmaf(hv.y,wv.y,fmaf(hv.z,wv.z,fmaf(hv.w,wv.w,accj[j]))));
        }
    }
    float acc2=h2_b[0];
    #pragma unroll
    for (int j=0;j<16;j++) acc2=fmaf(gelu_exact(accj[j]), h2_w[j], acc2);
    out[r0+tid]=1.0f/(1.0f+expf(-acc2));
}

extern "C" void kernel_launch(void* const* d_in, const int* in_sizes, int n_in,
                              void* d_out, int out_size, void* d_ws, size_t ws_size,
                              hipStream_t stream)
{
    const float* x     =(const float*)d_in[0];
    const float* in_w  =(const float*)d_in[1];
    const float* in_b  =(const float*)d_in[2];
    const float* conv_w=(const float*)d_in[3];
    const float* bn_g  =(const float*)d_in[4];
    const float* bn_b  =(const float*)d_in[5];
    const float* qkv_w =(const float*)d_in[6];
    const float* proj_w=(const float*)d_in[7];
    const float* proj_b=(const float*)d_in[8];
    const float* ln_g  =(const float*)d_in[9];
    const float* ln_b  =(const float*)d_in[10];
    const float* h1_w  =(const float*)d_in[11];
    const float* h1_b  =(const float*)d_in[12];
    const float* h2_w  =(const float*)d_in[13];
    const float* h2_b  =(const float*)d_in[14];

    float* bufA     = (float*)d_ws;
    float* bufB     = bufA + (size_t)BF*32;
    float* partials = bufB + (size_t)BF*32;
    float* stats    = partials + (size_t)NBLK*64;

    k_zero<<<1,256,0,stream>>>(stats);
    k_inproj<<<NBLK,256,0,stream>>>(x,in_w,in_b,bufA);
    for (int l=0;l<NLAYER;l++){
        float* cur = (l&1)? bufB : bufA;
        float* nxt = (l&1)? bufA : bufB;
        k_convstats<<<NBLK,256,0,stream>>>(cur, conv_w, l, partials);
        k_reduce<<<64,256,0,stream>>>(partials, stats + l*64);
        k_layer<<<NBLK,256,0,stream>>>(cur, nxt, stats+l*64, conv_w, bn_g, bn_b,
                                       qkv_w, proj_w, proj_b, ln_g, ln_b, l);
    }
    k_head<<<1028,256,0,stream>>>(bufA, h1_w,h1_b,h2_w,h2_b, (float*)d_out);
}

// Round 9
// 6547.974 us; speedup vs baseline: 1.6846x; 1.6846x over previous
//
#include <hip/hip_runtime.h>
#include <math.h>

// LightingSpeechShield — B=1024, F=257, C=32; fp32 in/out.
// R7: 1593 µs (k_layer LDS-issue-bound, scalar ds_reads).
// R8: 11030 µs REGRESSION — private arrays demoted to scratch (FETCH 3.2GB/WRITE 5GB
//     per dispatch = scratch traffic). Lesson: every private-array loop must be
//     #pragma unroll with static indices.
// R9: R8's correct phase logic + register-resident weights (unrolled float4),
//     sliding-window conv (10 broadcast b128 rows/thread instead of 768 scalar
//     reads), no weight LDS staging (LDS 46.3KB -> 3 blocks/CU).

#define BB 1024
#define FF 257
#define BF (BB*FF)
#define TILE 64
#define NT 5
#define NBLK (BB*NT)       // 5120
#define NLAYER 4
#define SQ 36              // qs/ks/vs/ys row stride (16B-aligned)

__device__ __forceinline__ float gelu_exact(float x){
    return 0.5f*x*(1.0f+erff(x*0.70710678118654752f));
}
__device__ __forceinline__ float dot4(float4 a, float4 b, float acc){
    return fmaf(a.x,b.x,fmaf(a.y,b.y,fmaf(a.z,b.z,fmaf(a.w,b.w,acc))));
}

__global__ __launch_bounds__(256) void k_zero(float* __restrict__ stats){
    stats[threadIdx.x]=0.0f;   // 256 = NLAYER*64
}

// ---------------- input projection: h = x(B,F,18) @ in_w(18,32) + in_b ----------------
__global__ __launch_bounds__(256) void k_inproj(const float* __restrict__ x,
        const float* __restrict__ in_w, const float* __restrict__ in_b,
        float* __restrict__ h)
{
    __shared__ float xs[TILE*18];
    int b = blockIdx.x / NT, t = blockIdx.x % NT, t0 = t*TILE;
    int tid = threadIdx.x;
    int nv = min(TILE, FF-t0);
    for (int i=tid;i<nv*18;i+=256) xs[i]=x[(size_t)(b*FF+t0)*18+i];
    __syncthreads();
    int co=tid&31, rq=tid>>5;
    float acc[8];
    float bias = in_b[co];
    #pragma unroll
    for (int k=0;k<8;k++) acc[k]=bias;
    #pragma unroll
    for (int ci=0;ci<18;ci++){
        float w = in_w[ci*32+co];              // coalesced, L2-resident
        #pragma unroll
        for (int k=0;k<8;k++){
            acc[k]=fmaf(xs[(rq*8+k)*18+ci], w, acc[k]);   // broadcast read
        }
    }
    #pragma unroll
    for (int k=0;k<8;k++){
        int r=rq*8+k;
        if (r<nv) h[(size_t)(b*FF+t0+r)*32+co]=acc[k];
    }
}

// ---------------- conv (sliding-window recompute) -> BN partial sums ----------------
__global__ __launch_bounds__(256) void k_convstats(const float* __restrict__ h,
        const float* __restrict__ conv_w, int layer, float* __restrict__ partials)
{
    __shared__ float hs[66*32];      // rows f = t0-1 .. t0+64
    __shared__ float ps[8][32];
    __shared__ float pq[8][32];
    int b=blockIdx.x/NT, t=blockIdx.x%NT, t0=t*TILE, tid=threadIdx.x;
    for (int i4=tid;i4<66*8;i4+=256){
        int r=i4>>3, f=t0-1+r;
        float4 v=make_float4(0.f,0.f,0.f,0.f);
        if (f>=0 && f<FF) v=*(const float4*)(h+(size_t)(b*FF+f)*32+(i4&7)*4);
        *(float4*)&hs[r*32+(i4&7)*4]=v;
    }
    __syncthreads();
    int co=tid&31, rq=tid>>5;
    const float* wl = conv_w + layer*3072;   // [wi][ci][co]
    float a[8];
    #pragma unroll
    for (int k=0;k<8;k++) a[k]=0.f;
    #pragma unroll
    for (int c4=0;c4<8;c4++){
        float4 w0=make_float4(wl[(0*32+c4*4+0)*32+co], wl[(0*32+c4*4+1)*32+co],
                              wl[(0*32+c4*4+2)*32+co], wl[(0*32+c4*4+3)*32+co]);
        float4 w1=make_float4(wl[(1*32+c4*4+0)*32+co], wl[(1*32+c4*4+1)*32+co],
                              wl[(1*32+c4*4+2)*32+co], wl[(1*32+c4*4+3)*32+co]);
        float4 w2=make_float4(wl[(2*32+c4*4+0)*32+co], wl[(2*32+c4*4+1)*32+co],
                              wl[(2*32+c4*4+2)*32+co], wl[(2*32+c4*4+3)*32+co]);
        #pragma unroll
        for (int p=0;p<10;p++){
            float4 hv=*(const float4*)&hs[(rq*8+p)*32+c4*4];   // broadcast
            if (p<=7)         a[p]   = dot4(hv,w0,a[p]);
            if (p>=1 && p<=8) a[p-1] = dot4(hv,w1,a[p-1]);
            if (p>=2)         a[p-2] = dot4(hv,w2,a[p-2]);
        }
    }
    float ssum=0.f, ssq=0.f;
    #pragma unroll
    for (int k=0;k<8;k++){
        if (t0+rq*8+k<FF){ ssum+=a[k]; ssq+=a[k]*a[k]; }
    }
    ps[rq][co]=ssum; pq[rq][co]=ssq;
    __syncthreads();
    if (tid<32){
        float s=0.f;
        #pragma unroll
        for(int q=0;q<8;q++) s+=ps[q][tid];
        partials[blockIdx.x*64+tid]=s;
    } else if (tid<64){
        int cc=tid-32;
        float s=0.f;
        #pragma unroll
        for(int q=0;q<8;q++) s+=pq[q][cc];
        partials[blockIdx.x*64+tid]=s;
    }
}

// ---------------- reduce partials -> stats[64] (sum | sumsq) ----------------
__global__ __launch_bounds__(256) void k_reduce(const float* __restrict__ partials,
        float* __restrict__ stats)
{
    __shared__ float sm[4][64];
    int tid=threadIdx.x, col=tid&63, rq=tid>>6;
    int r0=blockIdx.x*80;
    float s=0.f;
    for (int k=rq;k<80;k+=4) s += partials[(r0+k)*64+col];
    sm[rq][col]=s;
    __syncthreads();
    if (tid<64){
        float v=sm[0][tid]+sm[1][tid]+sm[2][tid]+sm[3][tid];
        atomicAdd(&stats[tid], v);
    }
}

// ---------------- fused layer ----------------
__global__ __launch_bounds__(256,3) void k_layer(const float* __restrict__ h,
        float* __restrict__ hn, const float* __restrict__ stats,
        const float* __restrict__ conv_w, const float* __restrict__ bn_g,
        const float* __restrict__ bn_b, const float* __restrict__ qkv_w,
        const float* __restrict__ proj_w, const float* __restrict__ proj_b,
        const float* __restrict__ ln_g, const float* __restrict__ ln_b, int layer)
{
    __shared__ float hs[67*32];            // rows f = t0-1 .. t0+65
    __shared__ float qs[66*SQ];            // becomes attn output in-place
    __shared__ float ks[66*SQ];
    __shared__ float vs[66*SQ];
    __shared__ float ys[64*SQ];

    int b=blockIdx.x/NT, t=blockIdx.x%NT, t0=t*TILE, tid=threadIdx.x;
    for (int i4=tid;i4<67*8;i4+=256){
        int r=i4>>3, f=t0-1+r;
        float4 v=make_float4(0.f,0.f,0.f,0.f);
        if (f>=0 && f<FF) v=*(const float4*)(h+(size_t)(b*FF+f)*32+(i4&7)*4);
        *(float4*)&hs[r*32+(i4&7)*4]=v;
    }
    __syncthreads();

    // ---- phase A (tid<192): qkv; thread owns one output column over 33 rows ----
    if (tid<192){
        int j=tid%96, g=tid/96;
        const float* qwp = qkv_w + layer*3072 + j;
        float4 wv[8];
        #pragma unroll
        for (int c4=0;c4<8;c4++)
            wv[c4]=make_float4(qwp[(c4*4+0)*96], qwp[(c4*4+1)*96],
                               qwp[(c4*4+2)*96], qwp[(c4*4+3)*96]);   // coalesced lanes
        int cbase = (j<32)? j : ((j<64)? j-32 : j-64);
        for (int rr=0;rr<33;rr++){
            int r=g*33+rr;
            if (t0+r<FF){
                float acc=0.f;
                #pragma unroll
                for (int c4=0;c4<8;c4++){
                    float4 hv=*(const float4*)&hs[(r+1)*32+c4*4];   // broadcast
                    acc=dot4(hv,wv[c4],acc);
                }
                if (j<32)      qs[r*SQ+cbase]=acc;
                else if (j<64) ks[r*SQ+cbase]=acc;
                else           vs[r*SQ+cbase]=acc;
            }
        }
    }
    // ---- phase B (all): sliding conv + BN + gelu -> ys ----
    int co=tid&31, rq=tid>>5;
    {
        float mu  = stats[co]*(1.0f/(float)BF);
        float var = stats[32+co]*(1.0f/(float)BF) - mu*mu;
        float rs  = rsqrtf(fmaxf(var,0.f)+1e-5f);
        float g   = bn_g[layer*32+co];
        float scv = g*rs;
        float shv = bn_b[layer*32+co] - mu*g*rs;
        const float* wl = conv_w + layer*3072;
        float a[8];
        #pragma unroll
        for (int k=0;k<8;k++) a[k]=0.f;
        #pragma unroll
        for (int c4=0;c4<8;c4++){
            float4 w0=make_float4(wl[(0*32+c4*4+0)*32+co], wl[(0*32+c4*4+1)*32+co],
                                  wl[(0*32+c4*4+2)*32+co], wl[(0*32+c4*4+3)*32+co]);
            float4 w1=make_float4(wl[(1*32+c4*4+0)*32+co], wl[(1*32+c4*4+1)*32+co],
                                  wl[(1*32+c4*4+2)*32+co], wl[(1*32+c4*4+3)*32+co]);
            float4 w2=make_float4(wl[(2*32+c4*4+0)*32+co], wl[(2*32+c4*4+1)*32+co],
                                  wl[(2*32+c4*4+2)*32+co], wl[(2*32+c4*4+3)*32+co]);
            #pragma unroll
            for (int p=0;p<10;p++){
                float4 hv=*(const float4*)&hs[(rq*8+p)*32+c4*4];   // broadcast
                if (p<=7)         a[p]   = dot4(hv,w0,a[p]);
                if (p>=1 && p<=8) a[p-1] = dot4(hv,w1,a[p-1]);
                if (p>=2)         a[p-2] = dot4(hv,w2,a[p-2]);
            }
        }
        #pragma unroll
        for (int k=0;k<8;k++){
            int r=rq*8+k;
            if (t0+r<FF) ys[r*SQ+co]=gelu_exact(fmaf(a[k],scv,shv));
        }
    }
    __syncthreads();

    // ---- phase C: banded attention (qs in-place) ----
    {
        int r=tid>>2, hh=tid&3, f=t0+r;
        if (f<FF){
            int base=hh*8;
            float4 qa=*(const float4*)&qs[r*SQ+base];
            float4 qb=*(const float4*)&qs[r*SQ+base+4];
            float s0, s1=-1e30f, s2=-1e30f;
            {
                float4 ka=*(const float4*)&ks[r*SQ+base];
                float4 kb=*(const float4*)&ks[r*SQ+base+4];
                s0=(dot4(qa,ka,dot4(qb,kb,0.f)))*0.35355339059327373f;
            }
            if (f+1<FF){
                float4 ka=*(const float4*)&ks[(r+1)*SQ+base];
                float4 kb=*(const float4*)&ks[(r+1)*SQ+base+4];
                s1=(dot4(qa,ka,dot4(qb,kb,0.f)))*0.35355339059327373f;
            }
            if (f+2<FF){
                float4 ka=*(const float4*)&ks[(r+2)*SQ+base];
                float4 kb=*(const float4*)&ks[(r+2)*SQ+base+4];
                s2=(dot4(qa,ka,dot4(qb,kb,0.f)))*0.35355339059327373f;
            }
            float mx=fmaxf(s0,fmaxf(s1,s2));
            float e0=expf(s0-mx);
            float e1=(f+1<FF)?expf(s1-mx):0.f;
            float e2=(f+2<FF)?expf(s2-mx):0.f;
            float inv=1.0f/(e0+e1+e2);
            float4 oa, ob;
            {
                float4 va=*(const float4*)&vs[r*SQ+base];
                float4 vb=*(const float4*)&vs[r*SQ+base+4];
                oa.x=e0*va.x; oa.y=e0*va.y; oa.z=e0*va.z; oa.w=e0*va.w;
                ob.x=e0*vb.x; ob.y=e0*vb.y; ob.z=e0*vb.z; ob.w=e0*vb.w;
            }
            if (f+1<FF){
                float4 va=*(const float4*)&vs[(r+1)*SQ+base];
                float4 vb=*(const float4*)&vs[(r+1)*SQ+base+4];
                oa.x=fmaf(e1,va.x,oa.x); oa.y=fmaf(e1,va.y,oa.y);
                oa.z=fmaf(e1,va.z,oa.z); oa.w=fmaf(e1,va.w,oa.w);
                ob.x=fmaf(e1,vb.x,ob.x); ob.y=fmaf(e1,vb.y,ob.y);
                ob.z=fmaf(e1,vb.z,ob.z); ob.w=fmaf(e1,vb.w,ob.w);
            }
            if (f+2<FF){
                float4 va=*(const float4*)&vs[(r+2)*SQ+base];
                float4 vb=*(const float4*)&vs[(r+2)*SQ+base+4];
                oa.x=fmaf(e2,va.x,oa.x); oa.y=fmaf(e2,va.y,oa.y);
                oa.z=fmaf(e2,va.z,oa.z); oa.w=fmaf(e2,va.w,oa.w);
                ob.x=fmaf(e2,vb.x,ob.x); ob.y=fmaf(e2,vb.y,ob.y);
                ob.z=fmaf(e2,vb.z,ob.z); ob.w=fmaf(e2,vb.w,ob.w);
            }
            oa.x*=inv; oa.y*=inv; oa.z*=inv; oa.w*=inv;
            ob.x*=inv; ob.y*=inv; ob.z*=inv; ob.w*=inv;
            *(float4*)&qs[r*SQ+base]=oa;
            *(float4*)&qs[r*SQ+base+4]=ob;
        }
    }
    __syncthreads();

    // ---- phase D: proj + residual into ys ----
    {
        const float* pwl = proj_w + layer*1024;
        float pbv = proj_b[layer*32+co];
        float d[8];
        #pragma unroll
        for (int k=0;k<8;k++) d[k]=pbv;
        #pragma unroll
        for (int c4=0;c4<8;c4++){
            float4 w=make_float4(pwl[(c4*4+0)*32+co], pwl[(c4*4+1)*32+co],
                                 pwl[(c4*4+2)*32+co], pwl[(c4*4+3)*32+co]);
            #pragma unroll
            for (int k=0;k<8;k++){
                float4 qv=*(const float4*)&qs[(rq*8+k)*SQ+c4*4];   // broadcast
                d[k]=dot4(qv,w,d[k]);
            }
        }
        #pragma unroll
        for (int k=0;k<8;k++){
            int r=rq*8+k;
            if (t0+r<FF) ys[r*SQ+co]+=d[k];
        }
    }
    __syncthreads();

    // ---- phase E+F: LayerNorm via shuffles + fused coalesced store ----
    {
        int r=tid>>2, q=tid&3, f=t0+r;
        if (f<FF){
            float4 a0=*(const float4*)&ys[r*SQ+q*8];
            float4 a1=*(const float4*)&ys[r*SQ+q*8+4];
            float s=a0.x+a0.y+a0.z+a0.w+a1.x+a1.y+a1.z+a1.w;
            s+=__shfl_xor(s,1); s+=__shfl_xor(s,2);
            float m=s*(1.0f/32.0f);
            float dd, v=0.f;
            dd=a0.x-m; v=fmaf(dd,dd,v); dd=a0.y-m; v=fmaf(dd,dd,v);
            dd=a0.z-m; v=fmaf(dd,dd,v); dd=a0.w-m; v=fmaf(dd,dd,v);
            dd=a1.x-m; v=fmaf(dd,dd,v); dd=a1.y-m; v=fmaf(dd,dd,v);
            dd=a1.z-m; v=fmaf(dd,dd,v); dd=a1.w-m; v=fmaf(dd,dd,v);
            v+=__shfl_xor(v,1); v+=__shfl_xor(v,2);
            float rsd=rsqrtf(fmaxf(v,0.f)*(1.0f/32.0f)+1e-5f);
            float4 g0=*(const float4*)&ln_g[layer*32+q*8];
            float4 g1=*(const float4*)&ln_g[layer*32+q*8+4];
            float4 b0=*(const float4*)&ln_b[layer*32+q*8];
            float4 b1=*(const float4*)&ln_b[layer*32+q*8+4];
            float4 o0, o1;
            o0.x=(a0.x-m)*rsd*g0.x+b0.x; o0.y=(a0.y-m)*rsd*g0.y+b0.y;
            o0.z=(a0.z-m)*rsd*g0.z+b0.z; o0.w=(a0.w-m)*rsd*g0.w+b0.w;
            o1.x=(a1.x-m)*rsd*g1.x+b1.x; o1.y=(a1.y-m)*rsd*g1.y+b1.y;
            o1.z=(a1.z-m)*rsd*g1.z+b1.z; o1.w=(a1.w-m)*rsd*g1.w+b1.w;
            *(float4*)(hn+(size_t)(b*FF+f)*32+q*8)=o0;
            *(float4*)(hn+(size_t)(b*FF+f)*32+q*8+4)=o1;
        }
    }
}

// ---------------- head: sigmoid(gelu(h@h1+b1)@h2+b2) ----------------
__global__ __launch_bounds__(256) void k_head(const float* __restrict__ h,
        const float* __restrict__ h1_w, const float* __restrict__ h1_b,
        const float* __restrict__ h2_w, const float* __restrict__ h2_b,
        float* __restrict__ out)
{
    __shared__ float hs[256*SQ];
    __shared__ float w1t[16*32];     // transposed h1_w
    int tid=threadIdx.x;
    int r0=blockIdx.x*256;           // BF == 1028*256 exactly
    for (int i4=tid;i4<256*8;i4+=256){
        float4 v=*(const float4*)(h+(size_t)r0*32+i4*4);
        *(float4*)&hs[(i4>>3)*SQ+(i4&7)*4]=v;
    }
    for (int i=tid;i<512;i+=256) w1t[i]=h1_w[(i&31)*16+(i>>5)];
    __syncthreads();
    float accj[16];
    #pragma unroll
    for (int j=0;j<16;j++) accj[j]=h1_b[j];
    #pragma unroll
    for (int c4=0;c4<8;c4++){
        float4 hv=*(const float4*)&hs[tid*SQ+c4*4];
        #pragma unroll
        for (int j=0;j<16;j++){
            float4 wv=*(const float4*)&w1t[j*32+c4*4];    // broadcast
            accj[j]=dot4(hv,wv,accj[j]);
        }
    }
    float acc2=h2_b[0];
    #pragma unroll
    for (int j=0;j<16;j++) acc2=fmaf(gelu_exact(accj[j]), h2_w[j], acc2);
    out[r0+tid]=1.0f/(1.0f+expf(-acc2));
}

extern "C" void kernel_launch(void* const* d_in, const int* in_sizes, int n_in,
                              void* d_out, int out_size, void* d_ws, size_t ws_size,
                              hipStream_t stream)
{
    const float* x     =(const float*)d_in[0];
    const float* in_w  =(const float*)d_in[1];
    const float* in_b  =(const float*)d_in[2];
    const float* conv_w=(const float*)d_in[3];
    const float* bn_g  =(const float*)d_in[4];
    const float* bn_b  =(const float*)d_in[5];
    const float* qkv_w =(const float*)d_in[6];
    const float* proj_w=(const float*)d_in[7];
    const float* proj_b=(const float*)d_in[8];
    const float* ln_g  =(const float*)d_in[9];
    const float* ln_b  =(const float*)d_in[10];
    const float* h1_w  =(const float*)d_in[11];
    const float* h1_b  =(const float*)d_in[12];
    const float* h2_w  =(const float*)d_in[13];
    const float* h2_b  =(const float*)d_in[14];

    float* bufA     = (float*)d_ws;
    float* bufB     = bufA + (size_t)BF*32;
    float* partials = bufB + (size_t)BF*32;
    float* stats    = partials + (size_t)NBLK*64;

    k_zero<<<1,256,0,stream>>>(stats);
    k_inproj<<<NBLK,256,0,stream>>>(x,in_w,in_b,bufA);
    for (int l=0;l<NLAYER;l++){
        float* cur = (l&1)? bufB : bufA;
        float* nxt = (l&1)? bufA : bufB;
        k_convstats<<<NBLK,256,0,stream>>>(cur, conv_w, l, partials);
        k_reduce<<<64,256,0,stream>>>(partials, stats + l*64);
        k_layer<<<NBLK,256,0,stream>>>(cur, nxt, stats+l*64, conv_w, bn_g, bn_b,
                                       qkv_w, proj_w, proj_b, ln_g, ln_b, l);
    }
    k_head<<<1028,256,0,stream>>>(bufA, h1_w,h1_b,h2_w,h2_b, (float*)d_out);
}

// Round 10
// 1310.169 us; speedup vs baseline: 8.4193x; 4.9978x over previous
//
#include <hip/hip_runtime.h>
#include <math.h>

// LightingSpeechShield — B=1024, F=257, C=32; fp32 in/out.
// R7: 1593 µs (k_layer LDS-issue-bound, scalar ds_reads, no scratch).
// R8: 11030 µs — private arrays demoted to scratch (FETCH 3.2GB/WRITE 5GB).
// R9: 6548 µs — #pragma unroll did NOT fix it (FETCH/WRITE still ~1.9GB,
//     VGPR=84): allocator under launch_bounds(256,3) demoted whole arrays.
// R10: ZERO private arrays — every accumulator/weight is a named scalar or
//     named float4; sliding conv written longhand; launch_bounds(256) only.

#define BB 1024
#define FF 257
#define BF (BB*FF)
#define TILE 64
#define NT 5
#define NBLK (BB*NT)       // 5120
#define NLAYER 4
#define SQ 36              // qs/ks/vs/ys row stride (16B-aligned)

__device__ __forceinline__ float gelu_exact(float x){
    return 0.5f*x*(1.0f+erff(x*0.70710678118654752f));
}
__device__ __forceinline__ float dot4(float4 a, float4 b, float acc){
    return fmaf(a.x,b.x,fmaf(a.y,b.y,fmaf(a.z,b.z,fmaf(a.w,b.w,acc))));
}

__global__ __launch_bounds__(256) void k_zero(float* __restrict__ stats){
    stats[threadIdx.x]=0.0f;   // 256 = NLAYER*64
}

// ---------------- input projection: h = x(B,F,18) @ in_w(18,32) + in_b ----------------
__global__ __launch_bounds__(256) void k_inproj(const float* __restrict__ x,
        const float* __restrict__ in_w, const float* __restrict__ in_b,
        float* __restrict__ h)
{
    __shared__ float xs[TILE*18];
    int b = blockIdx.x / NT, t = blockIdx.x % NT, t0 = t*TILE;
    int tid = threadIdx.x;
    int nv = min(TILE, FF-t0);
    for (int i=tid;i<nv*18;i+=256) xs[i]=x[(size_t)(b*FF+t0)*18+i];
    __syncthreads();
    int co=tid&31, rq=tid>>5, rbase=rq*8;
    float bias = in_b[co];
    float a0=bias,a1=bias,a2=bias,a3=bias,a4=bias,a5=bias,a6=bias,a7=bias;
    #pragma unroll
    for (int ci=0;ci<18;ci++){
        float w = in_w[ci*32+co];              // coalesced, L2-resident
        a0=fmaf(xs[(rbase+0)*18+ci],w,a0);
        a1=fmaf(xs[(rbase+1)*18+ci],w,a1);
        a2=fmaf(xs[(rbase+2)*18+ci],w,a2);
        a3=fmaf(xs[(rbase+3)*18+ci],w,a3);
        a4=fmaf(xs[(rbase+4)*18+ci],w,a4);
        a5=fmaf(xs[(rbase+5)*18+ci],w,a5);
        a6=fmaf(xs[(rbase+6)*18+ci],w,a6);
        a7=fmaf(xs[(rbase+7)*18+ci],w,a7);
    }
    size_t base=(size_t)(b*FF+t0+rbase)*32+co;
    if (rbase+0<nv) h[base+0*32]=a0;
    if (rbase+1<nv) h[base+1*32]=a1;
    if (rbase+2<nv) h[base+2*32]=a2;
    if (rbase+3<nv) h[base+3*32]=a3;
    if (rbase+4<nv) h[base+4*32]=a4;
    if (rbase+5<nv) h[base+5*32]=a5;
    if (rbase+6<nv) h[base+6*32]=a6;
    if (rbase+7<nv) h[base+7*32]=a7;
}

// sliding-window conv macro body: 10 broadcast b128 rows, 24 named dot4s.
#define CONV_C4_BODY(HSROW) \
    { float4 hv; \
      hv=*(const float4*)(HSROW+0*32); a0=dot4(hv,w0,a0); \
      hv=*(const float4*)(HSROW+1*32); a0=dot4(hv,w1,a0); a1=dot4(hv,w0,a1); \
      hv=*(const float4*)(HSROW+2*32); a0=dot4(hv,w2,a0); a1=dot4(hv,w1,a1); a2=dot4(hv,w0,a2); \
      hv=*(const float4*)(HSROW+3*32); a1=dot4(hv,w2,a1); a2=dot4(hv,w1,a2); a3=dot4(hv,w0,a3); \
      hv=*(const float4*)(HSROW+4*32); a2=dot4(hv,w2,a2); a3=dot4(hv,w1,a3); a4=dot4(hv,w0,a4); \
      hv=*(const float4*)(HSROW+5*32); a3=dot4(hv,w2,a3); a4=dot4(hv,w1,a4); a5=dot4(hv,w0,a5); \
      hv=*(const float4*)(HSROW+6*32); a4=dot4(hv,w2,a4); a5=dot4(hv,w1,a5); a6=dot4(hv,w0,a6); \
      hv=*(const float4*)(HSROW+7*32); a5=dot4(hv,w2,a5); a6=dot4(hv,w1,a6); a7=dot4(hv,w0,a7); \
      hv=*(const float4*)(HSROW+8*32); a6=dot4(hv,w2,a6); a7=dot4(hv,w1,a7); \
      hv=*(const float4*)(HSROW+9*32); a7=dot4(hv,w2,a7); }

// ---------------- conv (sliding-window recompute) -> BN partial sums ----------------
__global__ __launch_bounds__(256) void k_convstats(const float* __restrict__ h,
        const float* __restrict__ conv_w, int layer, float* __restrict__ partials)
{
    __shared__ float hs[66*32];      // rows f = t0-1 .. t0+64
    __shared__ float ps[8][32];
    __shared__ float pq[8][32];
    int b=blockIdx.x/NT, t=blockIdx.x%NT, t0=t*TILE, tid=threadIdx.x;
    for (int i4=tid;i4<66*8;i4+=256){
        int r=i4>>3, f=t0-1+r;
        float4 v=make_float4(0.f,0.f,0.f,0.f);
        if (f>=0 && f<FF) v=*(const float4*)(h+(size_t)(b*FF+f)*32+(i4&7)*4);
        *(float4*)&hs[r*32+(i4&7)*4]=v;
    }
    __syncthreads();
    int co=tid&31, rq=tid>>5, rbase=rq*8;
    const float* wl = conv_w + layer*3072 + co;   // [wi][ci][co]
    float a0=0.f,a1=0.f,a2=0.f,a3=0.f,a4=0.f,a5=0.f,a6=0.f,a7=0.f;
    #pragma unroll
    for (int c4=0;c4<8;c4++){
        const float* w=wl+c4*128;
        float4 w0=make_float4(w[0],   w[32],  w[64],  w[96]);
        float4 w1=make_float4(w[1024],w[1056],w[1088],w[1120]);
        float4 w2=make_float4(w[2048],w[2080],w[2112],w[2144]);
        const float* hb=&hs[rbase*32+c4*4];
        CONV_C4_BODY(hb)
    }
    float ssum=0.f, ssq=0.f;
    if (t0+rbase+0<FF){ ssum+=a0; ssq+=a0*a0; }
    if (t0+rbase+1<FF){ ssum+=a1; ssq+=a1*a1; }
    if (t0+rbase+2<FF){ ssum+=a2; ssq+=a2*a2; }
    if (t0+rbase+3<FF){ ssum+=a3; ssq+=a3*a3; }
    if (t0+rbase+4<FF){ ssum+=a4; ssq+=a4*a4; }
    if (t0+rbase+5<FF){ ssum+=a5; ssq+=a5*a5; }
    if (t0+rbase+6<FF){ ssum+=a6; ssq+=a6*a6; }
    if (t0+rbase+7<FF){ ssum+=a7; ssq+=a7*a7; }
    ps[rq][co]=ssum; pq[rq][co]=ssq;
    __syncthreads();
    if (tid<32){
        float s=0.f;
        #pragma unroll
        for(int q=0;q<8;q++) s+=ps[q][tid];
        partials[blockIdx.x*64+tid]=s;
    } else if (tid<64){
        int cc=tid-32;
        float s=0.f;
        #pragma unroll
        for(int q=0;q<8;q++) s+=pq[q][cc];
        partials[blockIdx.x*64+tid]=s;
    }
}

// ---------------- reduce partials -> stats[64] (sum | sumsq) ----------------
__global__ __launch_bounds__(256) void k_reduce(const float* __restrict__ partials,
        float* __restrict__ stats)
{
    __shared__ float sm[4][64];
    int tid=threadIdx.x, col=tid&63, rq=tid>>6;
    int r0=blockIdx.x*80;
    float s=0.f;
    for (int k=rq;k<80;k+=4) s += partials[(r0+k)*64+col];
    sm[rq][col]=s;
    __syncthreads();
    if (tid<64){
        float v=sm[0][tid]+sm[1][tid]+sm[2][tid]+sm[3][tid];
        atomicAdd(&stats[tid], v);
    }
}

// ---------------- fused layer ----------------
__global__ __launch_bounds__(256) void k_layer(const float* __restrict__ h,
        float* __restrict__ hn, const float* __restrict__ stats,
        const float* __restrict__ conv_w, const float* __restrict__ bn_g,
        const float* __restrict__ bn_b, const float* __restrict__ qkv_w,
        const float* __restrict__ proj_w, const float* __restrict__ proj_b,
        const float* __restrict__ ln_g, const float* __restrict__ ln_b, int layer)
{
    __shared__ float hs[67*32];            // rows f = t0-1 .. t0+65
    __shared__ float qs[66*SQ];            // becomes attn output in-place
    __shared__ float ks[66*SQ];
    __shared__ float vs[66*SQ];
    __shared__ float ys[64*SQ];

    int b=blockIdx.x/NT, t=blockIdx.x%NT, t0=t*TILE, tid=threadIdx.x;
    for (int i4=tid;i4<67*8;i4+=256){
        int r=i4>>3, f=t0-1+r;
        float4 v=make_float4(0.f,0.f,0.f,0.f);
        if (f>=0 && f<FF) v=*(const float4*)(h+(size_t)(b*FF+f)*32+(i4&7)*4);
        *(float4*)&hs[r*32+(i4&7)*4]=v;
    }
    __syncthreads();

    // ---- phase A (tid<192): qkv; thread owns one output column over 33 rows ----
    if (tid<192){
        int j=tid%96, g=tid/96;
        const float* qwp = qkv_w + layer*3072 + j;    // stride 96 per ci; lanes coalesced
        float4 wv0=make_float4(qwp[0*96], qwp[1*96], qwp[2*96], qwp[3*96]);
        float4 wv1=make_float4(qwp[4*96], qwp[5*96], qwp[6*96], qwp[7*96]);
        float4 wv2=make_float4(qwp[8*96], qwp[9*96], qwp[10*96],qwp[11*96]);
        float4 wv3=make_float4(qwp[12*96],qwp[13*96],qwp[14*96],qwp[15*96]);
        float4 wv4=make_float4(qwp[16*96],qwp[17*96],qwp[18*96],qwp[19*96]);
        float4 wv5=make_float4(qwp[20*96],qwp[21*96],qwp[22*96],qwp[23*96]);
        float4 wv6=make_float4(qwp[24*96],qwp[25*96],qwp[26*96],qwp[27*96]);
        float4 wv7=make_float4(qwp[28*96],qwp[29*96],qwp[30*96],qwp[31*96]);
        int cbase = (j<32)? j : ((j<64)? j-32 : j-64);
        float* dst = (j<32)? qs : ((j<64)? ks : vs);
        for (int rr=0;rr<33;rr++){
            int r=g*33+rr;
            if (t0+r<FF){
                const float* hr=&hs[(r+1)*32];
                float acc;
                acc=dot4(*(const float4*)(hr+ 0),wv0,0.f);
                acc=dot4(*(const float4*)(hr+ 4),wv1,acc);
                acc=dot4(*(const float4*)(hr+ 8),wv2,acc);
                acc=dot4(*(const float4*)(hr+12),wv3,acc);
                acc=dot4(*(const float4*)(hr+16),wv4,acc);
                acc=dot4(*(const float4*)(hr+20),wv5,acc);
                acc=dot4(*(const float4*)(hr+24),wv6,acc);
                acc=dot4(*(const float4*)(hr+28),wv7,acc);
                dst[r*SQ+cbase]=acc;
            }
        }
    }
    // ---- phase B (all): sliding conv + BN + gelu -> ys ----
    int co=tid&31, rq=tid>>5, rbase=rq*8;
    {
        float mu  = stats[co]*(1.0f/(float)BF);
        float var = stats[32+co]*(1.0f/(float)BF) - mu*mu;
        float rs  = rsqrtf(fmaxf(var,0.f)+1e-5f);
        float g   = bn_g[layer*32+co];
        float scv = g*rs;
        float shv = bn_b[layer*32+co] - mu*g*rs;
        const float* wl = conv_w + layer*3072 + co;
        float a0=0.f,a1=0.f,a2=0.f,a3=0.f,a4=0.f,a5=0.f,a6=0.f,a7=0.f;
        #pragma unroll
        for (int c4=0;c4<8;c4++){
            const float* w=wl+c4*128;
            float4 w0=make_float4(w[0],   w[32],  w[64],  w[96]);
            float4 w1=make_float4(w[1024],w[1056],w[1088],w[1120]);
            float4 w2=make_float4(w[2048],w[2080],w[2112],w[2144]);
            const float* hb=&hs[rbase*32+c4*4];
            CONV_C4_BODY(hb)
        }
        if (t0+rbase+0<FF) ys[(rbase+0)*SQ+co]=gelu_exact(fmaf(a0,scv,shv));
        if (t0+rbase+1<FF) ys[(rbase+1)*SQ+co]=gelu_exact(fmaf(a1,scv,shv));
        if (t0+rbase+2<FF) ys[(rbase+2)*SQ+co]=gelu_exact(fmaf(a2,scv,shv));
        if (t0+rbase+3<FF) ys[(rbase+3)*SQ+co]=gelu_exact(fmaf(a3,scv,shv));
        if (t0+rbase+4<FF) ys[(rbase+4)*SQ+co]=gelu_exact(fmaf(a4,scv,shv));
        if (t0+rbase+5<FF) ys[(rbase+5)*SQ+co]=gelu_exact(fmaf(a5,scv,shv));
        if (t0+rbase+6<FF) ys[(rbase+6)*SQ+co]=gelu_exact(fmaf(a6,scv,shv));
        if (t0+rbase+7<FF) ys[(rbase+7)*SQ+co]=gelu_exact(fmaf(a7,scv,shv));
    }
    __syncthreads();

    // ---- phase C: banded attention (qs in-place) ----
    {
        int r=tid>>2, hh=tid&3, f=t0+r;
        if (f<FF){
            int base=hh*8;
            float4 qa=*(const float4*)&qs[r*SQ+base];
            float4 qb=*(const float4*)&qs[r*SQ+base+4];
            float s0, s1=-1e30f, s2=-1e30f;
            s0=dot4(qa,*(const float4*)&ks[r*SQ+base],
               dot4(qb,*(const float4*)&ks[r*SQ+base+4],0.f))*0.35355339059327373f;
            if (f+1<FF)
                s1=dot4(qa,*(const float4*)&ks[(r+1)*SQ+base],
                   dot4(qb,*(const float4*)&ks[(r+1)*SQ+base+4],0.f))*0.35355339059327373f;
            if (f+2<FF)
                s2=dot4(qa,*(const float4*)&ks[(r+2)*SQ+base],
                   dot4(qb,*(const float4*)&ks[(r+2)*SQ+base+4],0.f))*0.35355339059327373f;
            float mx=fmaxf(s0,fmaxf(s1,s2));
            float e0=expf(s0-mx);
            float e1=(f+1<FF)?expf(s1-mx):0.f;
            float e2=(f+2<FF)?expf(s2-mx):0.f;
            float inv=1.0f/(e0+e1+e2);
            float4 va=*(const float4*)&vs[r*SQ+base];
            float4 vb=*(const float4*)&vs[r*SQ+base+4];
            float4 oa=make_float4(e0*va.x,e0*va.y,e0*va.z,e0*va.w);
            float4 ob=make_float4(e0*vb.x,e0*vb.y,e0*vb.z,e0*vb.w);
            if (f+1<FF){
                va=*(const float4*)&vs[(r+1)*SQ+base];
                vb=*(const float4*)&vs[(r+1)*SQ+base+4];
                oa.x=fmaf(e1,va.x,oa.x); oa.y=fmaf(e1,va.y,oa.y);
                oa.z=fmaf(e1,va.z,oa.z); oa.w=fmaf(e1,va.w,oa.w);
                ob.x=fmaf(e1,vb.x,ob.x); ob.y=fmaf(e1,vb.y,ob.y);
                ob.z=fmaf(e1,vb.z,ob.z); ob.w=fmaf(e1,vb.w,ob.w);
            }
            if (f+2<FF){
                va=*(const float4*)&vs[(r+2)*SQ+base];
                vb=*(const float4*)&vs[(r+2)*SQ+base+4];
                oa.x=fmaf(e2,va.x,oa.x); oa.y=fmaf(e2,va.y,oa.y);
                oa.z=fmaf(e2,va.z,oa.z); oa.w=fmaf(e2,va.w,oa.w);
                ob.x=fmaf(e2,vb.x,ob.x); ob.y=fmaf(e2,vb.y,ob.y);
                ob.z=fmaf(e2,vb.z,ob.z); ob.w=fmaf(e2,vb.w,ob.w);
            }
            oa.x*=inv; oa.y*=inv; oa.z*=inv; oa.w*=inv;
            ob.x*=inv; ob.y*=inv; ob.z*=inv; ob.w*=inv;
            *(float4*)&qs[r*SQ+base]=oa;
            *(float4*)&qs[r*SQ+base+4]=ob;
        }
    }
    __syncthreads();

    // ---- phase D: proj + residual into ys ----
    {
        const float* pwl = proj_w + layer*1024 + co;
        float pbv = proj_b[layer*32+co];
        float d0=pbv,d1=pbv,d2=pbv,d3=pbv,d4=pbv,d5=pbv,d6=pbv,d7=pbv;
        #pragma unroll
        for (int c4=0;c4<8;c4++){
            const float* w=pwl+c4*128;
            float4 wv=make_float4(w[0],w[32],w[64],w[96]);
            const float* qb=&qs[rbase*SQ+c4*4];
            d0=dot4(*(const float4*)(qb+0*SQ),wv,d0);
            d1=dot4(*(const float4*)(qb+1*SQ),wv,d1);
            d2=dot4(*(const float4*)(qb+2*SQ),wv,d2);
            d3=dot4(*(const float4*)(qb+3*SQ),wv,d3);
            d4=dot4(*(const float4*)(qb+4*SQ),wv,d4);
            d5=dot4(*(const float4*)(qb+5*SQ),wv,d5);
            d6=dot4(*(const float4*)(qb+6*SQ),wv,d6);
            d7=dot4(*(const float4*)(qb+7*SQ),wv,d7);
        }
        if (t0+rbase+0<FF) ys[(rbase+0)*SQ+co]+=d0;
        if (t0+rbase+1<FF) ys[(rbase+1)*SQ+co]+=d1;
        if (t0+rbase+2<FF) ys[(rbase+2)*SQ+co]+=d2;
        if (t0+rbase+3<FF) ys[(rbase+3)*SQ+co]+=d3;
        if (t0+rbase+4<FF) ys[(rbase+4)*SQ+co]+=d4;
        if (t0+rbase+5<FF) ys[(rbase+5)*SQ+co]+=d5;
        if (t0+rbase+6<FF) ys[(rbase+6)*SQ+co]+=d6;
        if (t0+rbase+7<FF) ys[(rbase+7)*SQ+co]+=d7;
    }
    __syncthreads();

    // ---- phase E+F: LayerNorm via shuffles + fused coalesced store ----
    {
        int r=tid>>2, q=tid&3, f=t0+r;
        if (f<FF){
            float4 a0=*(const float4*)&ys[r*SQ+q*8];
            float4 a1=*(const float4*)&ys[r*SQ+q*8+4];
            float s=a0.x+a0.y+a0.z+a0.w+a1.x+a1.y+a1.z+a1.w;
            s+=__shfl_xor(s,1); s+=__shfl_xor(s,2);
            float m=s*(1.0f/32.0f);
            float dd, v=0.f;
            dd=a0.x-m; v=fmaf(dd,dd,v); dd=a0.y-m; v=fmaf(dd,dd,v);
            dd=a0.z-m; v=fmaf(dd,dd,v); dd=a0.w-m; v=fmaf(dd,dd,v);
            dd=a1.x-m; v=fmaf(dd,dd,v); dd=a1.y-m; v=fmaf(dd,dd,v);
            dd=a1.z-m; v=fmaf(dd,dd,v); dd=a1.w-m; v=fmaf(dd,dd,v);
            v+=__shfl_xor(v,1); v+=__shfl_xor(v,2);
            float rsd=rsqrtf(fmaxf(v,0.f)*(1.0f/32.0f)+1e-5f);
            float4 g0=*(const float4*)&ln_g[layer*32+q*8];
            float4 g1=*(const float4*)&ln_g[layer*32+q*8+4];
            float4 b0=*(const float4*)&ln_b[layer*32+q*8];
            float4 b1=*(const float4*)&ln_b[layer*32+q*8+4];
            float4 o0, o1;
            o0.x=(a0.x-m)*rsd*g0.x+b0.x; o0.y=(a0.y-m)*rsd*g0.y+b0.y;
            o0.z=(a0.z-m)*rsd*g0.z+b0.z; o0.w=(a0.w-m)*rsd*g0.w+b0.w;
            o1.x=(a1.x-m)*rsd*g1.x+b1.x; o1.y=(a1.y-m)*rsd*g1.y+b1.y;
            o1.z=(a1.z-m)*rsd*g1.z+b1.z; o1.w=(a1.w-m)*rsd*g1.w+b1.w;
            *(float4*)(hn+(size_t)(b*FF+f)*32+q*8)=o0;
            *(float4*)(hn+(size_t)(b*FF+f)*32+q*8+4)=o1;
        }
    }
}

// ---------------- head: sigmoid(gelu(h@h1+b1)@h2+b2) ----------------
__global__ __launch_bounds__(256) void k_head(const float* __restrict__ h,
        const float* __restrict__ h1_w, const float* __restrict__ h1_b,
        const float* __restrict__ h2_w, const float* __restrict__ h2_b,
        float* __restrict__ out)
{
    __shared__ float hs[256*SQ];
    __shared__ float w1t[16*32];     // transposed h1_w
    int tid=threadIdx.x;
    int r0=blockIdx.x*256;           // BF == 1028*256 exactly
    for (int i4=tid;i4<256*8;i4+=256){
        float4 v=*(const float4*)(h+(size_t)r0*32+i4*4);
        *(float4*)&hs[(i4>>3)*SQ+(i4&7)*4]=v;
    }
    for (int i=tid;i<512;i+=256) w1t[i]=h1_w[(i&31)*16+(i>>5)];
    __syncthreads();
    float4 hv0=*(const float4*)&hs[tid*SQ+ 0];
    float4 hv1=*(const float4*)&hs[tid*SQ+ 4];
    float4 hv2=*(const float4*)&hs[tid*SQ+ 8];
    float4 hv3=*(const float4*)&hs[tid*SQ+12];
    float4 hv4=*(const float4*)&hs[tid*SQ+16];
    float4 hv5=*(const float4*)&hs[tid*SQ+20];
    float4 hv6=*(const float4*)&hs[tid*SQ+24];
    float4 hv7=*(const float4*)&hs[tid*SQ+28];
    float acc2=h2_b[0];
    #pragma unroll
    for (int j=0;j<16;j++){
        const float* wr=&w1t[j*32];
        float aj=h1_b[j];
        aj=dot4(hv0,*(const float4*)(wr+ 0),aj);
        aj=dot4(hv1,*(const float4*)(wr+ 4),aj);
        aj=dot4(hv2,*(const float4*)(wr+ 8),aj);
        aj=dot4(hv3,*(const float4*)(wr+12),aj);
        aj=dot4(hv4,*(const float4*)(wr+16),aj);
        aj=dot4(hv5,*(const float4*)(wr+20),aj);
        aj=dot4(hv6,*(const float4*)(wr+24),aj);
        aj=dot4(hv7,*(const float4*)(wr+28),aj);
        acc2=fmaf(gelu_exact(aj), h2_w[j], acc2);
    }
    out[r0+tid]=1.0f/(1.0f+expf(-acc2));
}

extern "C" void kernel_launch(void* const* d_in, const int* in_sizes, int n_in,
                              void* d_out, int out_size, void* d_ws, size_t ws_size,
                              hipStream_t stream)
{
    const float* x     =(const float*)d_in[0];
    const float* in_w  =(const float*)d_in[1];
    const float* in_b  =(const float*)d_in[2];
    const float* conv_w=(const float*)d_in[3];
    const float* bn_g  =(const float*)d_in[4];
    const float* bn_b  =(const float*)d_in[5];
    const float* qkv_w =(const float*)d_in[6];
    const float* proj_w=(const float*)d_in[7];
    const float* proj_b=(const float*)d_in[8];
    const float* ln_g  =(const float*)d_in[9];
    const float* ln_b  =(const float*)d_in[10];
    const float* h1_w  =(const float*)d_in[11];
    const float* h1_b  =(const float*)d_in[12];
    const float* h2_w  =(const float*)d_in[13];
    const float* h2_b  =(const float*)d_in[14];

    float* bufA     = (float*)d_ws;
    float* bufB     = bufA + (size_t)BF*32;
    float* partials = bufB + (size_t)BF*32;
    float* stats    = partials + (size_t)NBLK*64;

    k_zero<<<1,256,0,stream>>>(stats);
    k_inproj<<<NBLK,256,0,stream>>>(x,in_w,in_b,bufA);
    for (int l=0;l<NLAYER;l++){
        float* cur = (l&1)? bufB : bufA;
        float* nxt = (l&1)? bufA : bufB;
        k_convstats<<<NBLK,256,0,stream>>>(cur, conv_w, l, partials);
        k_reduce<<<64,256,0,stream>>>(partials, stats + l*64);
        k_layer<<<NBLK,256,0,stream>>>(cur, nxt, stats+l*64, conv_w, bn_g, bn_b,
                                       qkv_w, proj_w, proj_b, ln_g, ln_b, l);
    }
    k_head<<<1028,256,0,stream>>>(bufA, h1_w,h1_b,h2_w,h2_b, (float*)d_out);
}

// Round 11
// 728.796 us; speedup vs baseline: 15.1355x; 1.7977x over previous
//
#include <hip/hip_runtime.h>
#include <math.h>

// LightingSpeechShield — B=1024, F=257, C=32; fp32 in/out.
// R7: 1593 µs (LDS-issue-bound). R8/R9: scratch regressions (arrays→scratch).
// R10: 1310 µs — scratch gone (FETCH 17MB/WRITE 33MB legit) but VGPR=224
//      (full c4 unroll hoists ~128 VGPRs of weights) -> 2 waves/SIMD, VALUBusy 31%.
// R11: #pragma unroll 1 on weight-streaming loops (3 float4 weights live) +
//      ys LDS buffer deleted (conv result in y0..y7 regs, shuffle-LN fused with
//      store). LDS 46.6->37.1KB (4 blocks/CU), barriers 4->3.

#define BB 1024
#define FF 257
#define BF (BB*FF)
#define TILE 64
#define NT 5
#define NBLK (BB*NT)       // 5120
#define NLAYER 4
#define SQ 36              // qs/ks/vs row stride (16B-aligned)

__device__ __forceinline__ float gelu_exact(float x){
    return 0.5f*x*(1.0f+erff(x*0.70710678118654752f));
}
__device__ __forceinline__ float dot4(float4 a, float4 b, float acc){
    return fmaf(a.x,b.x,fmaf(a.y,b.y,fmaf(a.z,b.z,fmaf(a.w,b.w,acc))));
}

__global__ __launch_bounds__(256) void k_zero(float* __restrict__ stats){
    stats[threadIdx.x]=0.0f;   // 256 = NLAYER*64
}

// ---------------- input projection: h = x(B,F,18) @ in_w(18,32) + in_b ----------------
__global__ __launch_bounds__(256) void k_inproj(const float* __restrict__ x,
        const float* __restrict__ in_w, const float* __restrict__ in_b,
        float* __restrict__ h)
{
    __shared__ float xs[TILE*18];
    int b = blockIdx.x / NT, t = blockIdx.x % NT, t0 = t*TILE;
    int tid = threadIdx.x;
    int nv = min(TILE, FF-t0);
    for (int i=tid;i<nv*18;i+=256) xs[i]=x[(size_t)(b*FF+t0)*18+i];
    __syncthreads();
    int co=tid&31, rq=tid>>5, rbase=rq*8;
    float bias = in_b[co];
    float a0=bias,a1=bias,a2=bias,a3=bias,a4=bias,a5=bias,a6=bias,a7=bias;
    #pragma unroll
    for (int ci=0;ci<18;ci++){
        float w = in_w[ci*32+co];
        a0=fmaf(xs[(rbase+0)*18+ci],w,a0);
        a1=fmaf(xs[(rbase+1)*18+ci],w,a1);
        a2=fmaf(xs[(rbase+2)*18+ci],w,a2);
        a3=fmaf(xs[(rbase+3)*18+ci],w,a3);
        a4=fmaf(xs[(rbase+4)*18+ci],w,a4);
        a5=fmaf(xs[(rbase+5)*18+ci],w,a5);
        a6=fmaf(xs[(rbase+6)*18+ci],w,a6);
        a7=fmaf(xs[(rbase+7)*18+ci],w,a7);
    }
    size_t base=(size_t)(b*FF+t0+rbase)*32+co;
    if (rbase+0<nv) h[base+0*32]=a0;
    if (rbase+1<nv) h[base+1*32]=a1;
    if (rbase+2<nv) h[base+2*32]=a2;
    if (rbase+3<nv) h[base+3*32]=a3;
    if (rbase+4<nv) h[base+4*32]=a4;
    if (rbase+5<nv) h[base+5*32]=a5;
    if (rbase+6<nv) h[base+6*32]=a6;
    if (rbase+7<nv) h[base+7*32]=a7;
}

// sliding-window conv body: 10 broadcast b128 rows, 24 named dot4s.
#define CONV_C4_BODY(HSROW) \
    { float4 hv; \
      hv=*(const float4*)(HSROW+0*32); a0=dot4(hv,w0,a0); \
      hv=*(const float4*)(HSROW+1*32); a0=dot4(hv,w1,a0); a1=dot4(hv,w0,a1); \
      hv=*(const float4*)(HSROW+2*32); a0=dot4(hv,w2,a0); a1=dot4(hv,w1,a1); a2=dot4(hv,w0,a2); \
      hv=*(const float4*)(HSROW+3*32); a1=dot4(hv,w2,a1); a2=dot4(hv,w1,a2); a3=dot4(hv,w0,a3); \
      hv=*(const float4*)(HSROW+4*32); a2=dot4(hv,w2,a2); a3=dot4(hv,w1,a3); a4=dot4(hv,w0,a4); \
      hv=*(const float4*)(HSROW+5*32); a3=dot4(hv,w2,a3); a4=dot4(hv,w1,a4); a5=dot4(hv,w0,a5); \
      hv=*(const float4*)(HSROW+6*32); a4=dot4(hv,w2,a4); a5=dot4(hv,w1,a5); a6=dot4(hv,w0,a6); \
      hv=*(const float4*)(HSROW+7*32); a5=dot4(hv,w2,a5); a6=dot4(hv,w1,a6); a7=dot4(hv,w0,a7); \
      hv=*(const float4*)(HSROW+8*32); a6=dot4(hv,w2,a6); a7=dot4(hv,w1,a7); \
      hv=*(const float4*)(HSROW+9*32); a7=dot4(hv,w2,a7); }

// ---------------- conv (sliding-window recompute) -> BN partial sums ----------------
__global__ __launch_bounds__(256) void k_convstats(const float* __restrict__ h,
        const float* __restrict__ conv_w, int layer, float* __restrict__ partials)
{
    __shared__ float hs[66*32];      // rows f = t0-1 .. t0+64
    __shared__ float ps[8][32];
    __shared__ float pq[8][32];
    int b=blockIdx.x/NT, t=blockIdx.x%NT, t0=t*TILE, tid=threadIdx.x;
    for (int i4=tid;i4<66*8;i4+=256){
        int r=i4>>3, f=t0-1+r;
        float4 v=make_float4(0.f,0.f,0.f,0.f);
        if (f>=0 && f<FF) v=*(const float4*)(h+(size_t)(b*FF+f)*32+(i4&7)*4);
        *(float4*)&hs[r*32+(i4&7)*4]=v;
    }
    __syncthreads();
    int co=tid&31, rq=tid>>5, rbase=rq*8;
    const float* wl = conv_w + layer*3072 + co;   // [wi][ci][co]
    float a0=0.f,a1=0.f,a2=0.f,a3=0.f,a4=0.f,a5=0.f,a6=0.f,a7=0.f;
    #pragma unroll 1
    for (int c4=0;c4<8;c4++){
        const float* w=wl+c4*128;
        float4 w0=make_float4(w[0],   w[32],  w[64],  w[96]);
        float4 w1=make_float4(w[1024],w[1056],w[1088],w[1120]);
        float4 w2=make_float4(w[2048],w[2080],w[2112],w[2144]);
        const float* hb=&hs[rbase*32+c4*4];
        CONV_C4_BODY(hb)
    }
    float ssum=0.f, ssq=0.f;
    if (t0+rbase+0<FF){ ssum+=a0; ssq+=a0*a0; }
    if (t0+rbase+1<FF){ ssum+=a1; ssq+=a1*a1; }
    if (t0+rbase+2<FF){ ssum+=a2; ssq+=a2*a2; }
    if (t0+rbase+3<FF){ ssum+=a3; ssq+=a3*a3; }
    if (t0+rbase+4<FF){ ssum+=a4; ssq+=a4*a4; }
    if (t0+rbase+5<FF){ ssum+=a5; ssq+=a5*a5; }
    if (t0+rbase+6<FF){ ssum+=a6; ssq+=a6*a6; }
    if (t0+rbase+7<FF){ ssum+=a7; ssq+=a7*a7; }
    ps[rq][co]=ssum; pq[rq][co]=ssq;
    __syncthreads();
    if (tid<32){
        float s=0.f;
        #pragma unroll
        for(int q=0;q<8;q++) s+=ps[q][tid];
        partials[blockIdx.x*64+tid]=s;
    } else if (tid<64){
        int cc=tid-32;
        float s=0.f;
        #pragma unroll
        for(int q=0;q<8;q++) s+=pq[q][cc];
        partials[blockIdx.x*64+tid]=s;
    }
}

// ---------------- reduce partials -> stats[64] (sum | sumsq) ----------------
__global__ __launch_bounds__(256) void k_reduce(const float* __restrict__ partials,
        float* __restrict__ stats)
{
    __shared__ float sm[4][64];
    int tid=threadIdx.x, col=tid&63, rq=tid>>6;
    int r0=blockIdx.x*80;
    float s=0.f;
    for (int k=rq;k<80;k+=4) s += partials[(r0+k)*64+col];
    sm[rq][col]=s;
    __syncthreads();
    if (tid<64){
        float v=sm[0][tid]+sm[1][tid]+sm[2][tid]+sm[3][tid];
        atomicAdd(&stats[tid], v);
    }
}

// LayerNorm-over-32-lanes + guarded store, all in registers/shuffles.
#define LN_STORE(Y,K) { \
    float s=(Y); \
    s+=__shfl_xor(s,1); s+=__shfl_xor(s,2); s+=__shfl_xor(s,4); \
    s+=__shfl_xor(s,8); s+=__shfl_xor(s,16); \
    float m=s*(1.0f/32.0f); \
    float dd=(Y)-m; float v=dd*dd; \
    v+=__shfl_xor(v,1); v+=__shfl_xor(v,2); v+=__shfl_xor(v,4); \
    v+=__shfl_xor(v,8); v+=__shfl_xor(v,16); \
    float rsd=rsqrtf(v*(1.0f/32.0f)+1e-5f); \
    if (t0+rbase+(K)<FF) hn[(size_t)(b*FF+t0+rbase+(K))*32+co]=dd*rsd*lgv+lbv; }

// ---------------- fused layer ----------------
__global__ __launch_bounds__(256) void k_layer(const float* __restrict__ h,
        float* __restrict__ hn, const float* __restrict__ stats,
        const float* __restrict__ conv_w, const float* __restrict__ bn_g,
        const float* __restrict__ bn_b, const float* __restrict__ qkv_w,
        const float* __restrict__ proj_w, const float* __restrict__ proj_b,
        const float* __restrict__ ln_g, const float* __restrict__ ln_b, int layer)
{
    __shared__ float hs[67*32];            // rows f = t0-1 .. t0+65
    __shared__ float qs[66*SQ];            // becomes attn output in-place
    __shared__ float ks[66*SQ];
    __shared__ float vs[66*SQ];

    int b=blockIdx.x/NT, t=blockIdx.x%NT, t0=t*TILE, tid=threadIdx.x;
    for (int i4=tid;i4<67*8;i4+=256){
        int r=i4>>3, f=t0-1+r;
        float4 v=make_float4(0.f,0.f,0.f,0.f);
        if (f>=0 && f<FF) v=*(const float4*)(h+(size_t)(b*FF+f)*32+(i4&7)*4);
        *(float4*)&hs[r*32+(i4&7)*4]=v;
    }
    __syncthreads();

    // ---- phase A (tid<192): qkv; thread owns one output column over 33 rows ----
    if (tid<192){
        int j=tid%96, g=tid/96;
        const float* qwp = qkv_w + layer*3072 + j;    // lanes coalesced
        float4 wv0=make_float4(qwp[0*96], qwp[1*96], qwp[2*96], qwp[3*96]);
        float4 wv1=make_float4(qwp[4*96], qwp[5*96], qwp[6*96], qwp[7*96]);
        float4 wv2=make_float4(qwp[8*96], qwp[9*96], qwp[10*96],qwp[11*96]);
        float4 wv3=make_float4(qwp[12*96],qwp[13*96],qwp[14*96],qwp[15*96]);
        float4 wv4=make_float4(qwp[16*96],qwp[17*96],qwp[18*96],qwp[19*96]);
        float4 wv5=make_float4(qwp[20*96],qwp[21*96],qwp[22*96],qwp[23*96]);
        float4 wv6=make_float4(qwp[24*96],qwp[25*96],qwp[26*96],qwp[27*96]);
        float4 wv7=make_float4(qwp[28*96],qwp[29*96],qwp[30*96],qwp[31*96]);
        int cbase = (j<32)? j : ((j<64)? j-32 : j-64);
        float* dst = (j<32)? qs : ((j<64)? ks : vs);
        #pragma unroll 1
        for (int rr=0;rr<33;rr++){
            int r=g*33+rr;
            if (t0+r<FF){
                const float* hr=&hs[(r+1)*32];
                float acc;
                acc=dot4(*(const float4*)(hr+ 0),wv0,0.f);
                acc=dot4(*(const float4*)(hr+ 4),wv1,acc);
                acc=dot4(*(const float4*)(hr+ 8),wv2,acc);
                acc=dot4(*(const float4*)(hr+12),wv3,acc);
                acc=dot4(*(const float4*)(hr+16),wv4,acc);
                acc=dot4(*(const float4*)(hr+20),wv5,acc);
                acc=dot4(*(const float4*)(hr+24),wv6,acc);
                acc=dot4(*(const float4*)(hr+28),wv7,acc);
                dst[r*SQ+cbase]=acc;
            }
        }
    }
    // ---- phase B (all): sliding conv + BN + gelu -> y0..y7 registers ----
    int co=tid&31, rq=tid>>5, rbase=rq*8;
    float y0,y1,y2,y3,y4,y5,y6,y7;
    {
        float mu  = stats[co]*(1.0f/(float)BF);
        float var = stats[32+co]*(1.0f/(float)BF) - mu*mu;
        float rs  = rsqrtf(fmaxf(var,0.f)+1e-5f);
        float g   = bn_g[layer*32+co];
        float scv = g*rs;
        float shv = bn_b[layer*32+co] - mu*g*rs;
        const float* wl = conv_w + layer*3072 + co;
        float a0=0.f,a1=0.f,a2=0.f,a3=0.f,a4=0.f,a5=0.f,a6=0.f,a7=0.f;
        #pragma unroll 1
        for (int c4=0;c4<8;c4++){
            const float* w=wl+c4*128;
            float4 w0=make_float4(w[0],   w[32],  w[64],  w[96]);
            float4 w1=make_float4(w[1024],w[1056],w[1088],w[1120]);
            float4 w2=make_float4(w[2048],w[2080],w[2112],w[2144]);
            const float* hb=&hs[rbase*32+c4*4];
            CONV_C4_BODY(hb)
        }
        y0=gelu_exact(fmaf(a0,scv,shv));
        y1=gelu_exact(fmaf(a1,scv,shv));
        y2=gelu_exact(fmaf(a2,scv,shv));
        y3=gelu_exact(fmaf(a3,scv,shv));
        y4=gelu_exact(fmaf(a4,scv,shv));
        y5=gelu_exact(fmaf(a5,scv,shv));
        y6=gelu_exact(fmaf(a6,scv,shv));
        y7=gelu_exact(fmaf(a7,scv,shv));
    }
    __syncthreads();

    // ---- phase C: banded attention (qs in-place) ----
    {
        int r=tid>>2, hh=tid&3, f=t0+r;
        if (f<FF){
            int base=hh*8;
            float4 qa=*(const float4*)&qs[r*SQ+base];
            float4 qb=*(const float4*)&qs[r*SQ+base+4];
            float s0, s1=-1e30f, s2=-1e30f;
            s0=dot4(qa,*(const float4*)&ks[r*SQ+base],
               dot4(qb,*(const float4*)&ks[r*SQ+base+4],0.f))*0.35355339059327373f;
            if (f+1<FF)
                s1=dot4(qa,*(const float4*)&ks[(r+1)*SQ+base],
                   dot4(qb,*(const float4*)&ks[(r+1)*SQ+base+4],0.f))*0.35355339059327373f;
            if (f+2<FF)
                s2=dot4(qa,*(const float4*)&ks[(r+2)*SQ+base],
                   dot4(qb,*(const float4*)&ks[(r+2)*SQ+base+4],0.f))*0.35355339059327373f;
            float mx=fmaxf(s0,fmaxf(s1,s2));
            float e0=expf(s0-mx);
            float e1=(f+1<FF)?expf(s1-mx):0.f;
            float e2=(f+2<FF)?expf(s2-mx):0.f;
            float inv=1.0f/(e0+e1+e2);
            float4 va=*(const float4*)&vs[r*SQ+base];
            float4 vb=*(const float4*)&vs[r*SQ+base+4];
            float4 oa=make_float4(e0*va.x,e0*va.y,e0*va.z,e0*va.w);
            float4 ob=make_float4(e0*vb.x,e0*vb.y,e0*vb.z,e0*vb.w);
            if (f+1<FF){
                va=*(const float4*)&vs[(r+1)*SQ+base];
                vb=*(const float4*)&vs[(r+1)*SQ+base+4];
                oa.x=fmaf(e1,va.x,oa.x); oa.y=fmaf(e1,va.y,oa.y);
                oa.z=fmaf(e1,va.z,oa.z); oa.w=fmaf(e1,va.w,oa.w);
                ob.x=fmaf(e1,vb.x,ob.x); ob.y=fmaf(e1,vb.y,ob.y);
                ob.z=fmaf(e1,vb.z,ob.z); ob.w=fmaf(e1,vb.w,ob.w);
            }
            if (f+2<FF){
                va=*(const float4*)&vs[(r+2)*SQ+base];
                vb=*(const float4*)&vs[(r+2)*SQ+base+4];
                oa.x=fmaf(e2,va.x,oa.x); oa.y=fmaf(e2,va.y,oa.y);
                oa.z=fmaf(e2,va.z,oa.z); oa.w=fmaf(e2,va.w,oa.w);
                ob.x=fmaf(e2,vb.x,ob.x); ob.y=fmaf(e2,vb.y,ob.y);
                ob.z=fmaf(e2,vb.z,ob.z); ob.w=fmaf(e2,vb.w,ob.w);
            }
            oa.x*=inv; oa.y*=inv; oa.z*=inv; oa.w*=inv;
            ob.x*=inv; ob.y*=inv; ob.z*=inv; ob.w*=inv;
            *(float4*)&qs[r*SQ+base]=oa;
            *(float4*)&qs[r*SQ+base+4]=ob;
        }
    }
    __syncthreads();

    // ---- phase D: proj + residual into y regs ----
    {
        const float* pwl = proj_w + layer*1024 + co;
        float pbv = proj_b[layer*32+co];
        float d0=pbv,d1=pbv,d2=pbv,d3=pbv,d4=pbv,d5=pbv,d6=pbv,d7=pbv;
        #pragma unroll 1
        for (int c4=0;c4<8;c4++){
            const float* w=pwl+c4*128;
            float4 wv=make_float4(w[0],w[32],w[64],w[96]);
            const float* qb=&qs[rbase*SQ+c4*4];
            d0=dot4(*(const float4*)(qb+0*SQ),wv,d0);
            d1=dot4(*(const float4*)(qb+1*SQ),wv,d1);
            d2=dot4(*(const float4*)(qb+2*SQ),wv,d2);
            d3=dot4(*(const float4*)(qb+3*SQ),wv,d3);
            d4=dot4(*(const float4*)(qb+4*SQ),wv,d4);
            d5=dot4(*(const float4*)(qb+5*SQ),wv,d5);
            d6=dot4(*(const float4*)(qb+6*SQ),wv,d6);
            d7=dot4(*(const float4*)(qb+7*SQ),wv,d7);
        }
        y0+=d0; y1+=d1; y2+=d2; y3+=d3; y4+=d4; y5+=d5; y6+=d6; y7+=d7;
    }

    // ---- phase E: LayerNorm via lane shuffles + fused store (no LDS, no barrier) ----
    {
        float lgv=ln_g[layer*32+co];
        float lbv=ln_b[layer*32+co];
        LN_STORE(y0,0) LN_STORE(y1,1) LN_STORE(y2,2) LN_STORE(y3,3)
        LN_STORE(y4,4) LN_STORE(y5,5) LN_STORE(y6,6) LN_STORE(y7,7)
    }
}

// ---------------- head: sigmoid(gelu(h@h1+b1)@h2+b2) ----------------
__global__ __launch_bounds__(256) void k_head(const float* __restrict__ h,
        const float* __restrict__ h1_w, const float* __restrict__ h1_b,
        const float* __restrict__ h2_w, const float* __restrict__ h2_b,
        float* __restrict__ out)
{
    __shared__ float hs[256*SQ];
    __shared__ float w1t[16*32];     // transposed h1_w
    int tid=threadIdx.x;
    int r0=blockIdx.x*256;           // BF == 1028*256 exactly
    for (int i4=tid;i4<256*8;i4+=256){
        float4 v=*(const float4*)(h+(size_t)r0*32+i4*4);
        *(float4*)&hs[(i4>>3)*SQ+(i4&7)*4]=v;
    }
    for (int i=tid;i<512;i+=256) w1t[i]=h1_w[(i&31)*16+(i>>5)];
    __syncthreads();
    float4 hv0=*(const float4*)&hs[tid*SQ+ 0];
    float4 hv1=*(const float4*)&hs[tid*SQ+ 4];
    float4 hv2=*(const float4*)&hs[tid*SQ+ 8];
    float4 hv3=*(const float4*)&hs[tid*SQ+12];
    float4 hv4=*(const float4*)&hs[tid*SQ+16];
    float4 hv5=*(const float4*)&hs[tid*SQ+20];
    float4 hv6=*(const float4*)&hs[tid*SQ+24];
    float4 hv7=*(const float4*)&hs[tid*SQ+28];
    float acc2=h2_b[0];
    #pragma unroll
    for (int j=0;j<16;j++){
        const float* wr=&w1t[j*32];
        float aj=h1_b[j];
        aj=dot4(hv0,*(const float4*)(wr+ 0),aj);
        aj=dot4(hv1,*(const float4*)(wr+ 4),aj);
        aj=dot4(hv2,*(const float4*)(wr+ 8),aj);
        aj=dot4(hv3,*(const float4*)(wr+12),aj);
        aj=dot4(hv4,*(const float4*)(wr+16),aj);
        aj=dot4(hv5,*(const float4*)(wr+20),aj);
        aj=dot4(hv6,*(const float4*)(wr+24),aj);
        aj=dot4(hv7,*(const float4*)(wr+28),aj);
        acc2=fmaf(gelu_exact(aj), h2_w[j], acc2);
    }
    out[r0+tid]=1.0f/(1.0f+expf(-acc2));
}

extern "C" void kernel_launch(void* const* d_in, const int* in_sizes, int n_in,
                              void* d_out, int out_size, void* d_ws, size_t ws_size,
                              hipStream_t stream)
{
    const float* x     =(const float*)d_in[0];
    const float* in_w  =(const float*)d_in[1];
    const float* in_b  =(const float*)d_in[2];
    const float* conv_w=(const float*)d_in[3];
    const float* bn_g  =(const float*)d_in[4];
    const float* bn_b  =(const float*)d_in[5];
    const float* qkv_w =(const float*)d_in[6];
    const float* proj_w=(const float*)d_in[7];
    const float* proj_b=(const float*)d_in[8];
    const float* ln_g  =(const float*)d_in[9];
    const float* ln_b  =(const float*)d_in[10];
    const float* h1_w  =(const float*)d_in[11];
    const float* h1_b  =(const float*)d_in[12];
    const float* h2_w  =(const float*)d_in[13];
    const float* h2_b  =(const float*)d_in[14];

    float* bufA     = (float*)d_ws;
    float* bufB     = bufA + (size_t)BF*32;
    float* partials = bufB + (size_t)BF*32;
    float* stats    = partials + (size_t)NBLK*64;

    k_zero<<<1,256,0,stream>>>(stats);
    k_inproj<<<NBLK,256,0,stream>>>(x,in_w,in_b,bufA);
    for (int l=0;l<NLAYER;l++){
        float* cur = (l&1)? bufB : bufA;
        float* nxt = (l&1)? bufA : bufB;
        k_convstats<<<NBLK,256,0,stream>>>(cur, conv_w, l, partials);
        k_reduce<<<64,256,0,stream>>>(partials, stats + l*64);
        k_layer<<<NBLK,256,0,stream>>>(cur, nxt, stats+l*64, conv_w, bn_g, bn_b,
                                       qkv_w, proj_w, proj_b, ln_g, ln_b, l);
    }
    k_head<<<1028,256,0,stream>>>(bufA, h1_w,h1_b,h2_w,h2_b, (float*)d_out);
}

// Round 12
// 712.576 us; speedup vs baseline: 15.4801x; 1.0228x over previous
//
#include <hip/hip_runtime.h>
#include <math.h>

// LightingSpeechShield — B=1024, F=257, C=32; fp32 in/out.
// R10: 1310 µs (VGPR=224, 2 waves/SIMD). R11: 729 µs (VGPR=64, VALUBusy 77%,
//      k_layer 127 µs — VALU-ISSUE-bound at ~5.8k instr/wave; phase A re-reads
//      the same hs rows phase B reads).
// R12: qkv merged INTO the conv sliding window (qkv row r uses hs[r+1] =
//      conv window rows 1..8): one hs read feeds up to 6 dot4s. Phase A
//      deleted. Edge k/v rows 64/65 via wave-0 half-wave extra accumulators.

#define BB 1024
#define FF 257
#define BF (BB*FF)
#define TILE 64
#define NT 5
#define NBLK (BB*NT)       // 5120
#define NLAYER 4
#define SQ 36              // qs/ks/vs row stride (16B-aligned)

__device__ __forceinline__ float gelu_exact(float x){
    return 0.5f*x*(1.0f+erff(x*0.70710678118654752f));
}
__device__ __forceinline__ float dot4(float4 a, float4 b, float acc){
    return fmaf(a.x,b.x,fmaf(a.y,b.y,fmaf(a.z,b.z,fmaf(a.w,b.w,acc))));
}

__global__ __launch_bounds__(256) void k_zero(float* __restrict__ stats){
    stats[threadIdx.x]=0.0f;   // 256 = NLAYER*64
}

// ---------------- input projection: h = x(B,F,18) @ in_w(18,32) + in_b ----------------
__global__ __launch_bounds__(256) void k_inproj(const float* __restrict__ x,
        const float* __restrict__ in_w, const float* __restrict__ in_b,
        float* __restrict__ h)
{
    __shared__ float xs[TILE*18];
    int b = blockIdx.x / NT, t = blockIdx.x % NT, t0 = t*TILE;
    int tid = threadIdx.x;
    int nv = min(TILE, FF-t0);
    for (int i=tid;i<nv*18;i+=256) xs[i]=x[(size_t)(b*FF+t0)*18+i];
    __syncthreads();
    int co=tid&31, rq=tid>>5, rbase=rq*8;
    float bias = in_b[co];
    float a0=bias,a1=bias,a2=bias,a3=bias,a4=bias,a5=bias,a6=bias,a7=bias;
    #pragma unroll
    for (int ci=0;ci<18;ci++){
        float w = in_w[ci*32+co];
        a0=fmaf(xs[(rbase+0)*18+ci],w,a0);
        a1=fmaf(xs[(rbase+1)*18+ci],w,a1);
        a2=fmaf(xs[(rbase+2)*18+ci],w,a2);
        a3=fmaf(xs[(rbase+3)*18+ci],w,a3);
        a4=fmaf(xs[(rbase+4)*18+ci],w,a4);
        a5=fmaf(xs[(rbase+5)*18+ci],w,a5);
        a6=fmaf(xs[(rbase+6)*18+ci],w,a6);
        a7=fmaf(xs[(rbase+7)*18+ci],w,a7);
    }
    size_t base=(size_t)(b*FF+t0+rbase)*32+co;
    if (rbase+0<nv) h[base+0*32]=a0;
    if (rbase+1<nv) h[base+1*32]=a1;
    if (rbase+2<nv) h[base+2*32]=a2;
    if (rbase+3<nv) h[base+3*32]=a3;
    if (rbase+4<nv) h[base+4*32]=a4;
    if (rbase+5<nv) h[base+5*32]=a5;
    if (rbase+6<nv) h[base+6*32]=a6;
    if (rbase+7<nv) h[base+7*32]=a7;
}

// sliding-window conv body: 10 broadcast b128 rows, 24 named dot4s.
#define CONV_C4_BODY(HSROW) \
    { float4 hv; \
      hv=*(const float4*)(HSROW+0*32); a0=dot4(hv,w0,a0); \
      hv=*(const float4*)(HSROW+1*32); a0=dot4(hv,w1,a0); a1=dot4(hv,w0,a1); \
      hv=*(const float4*)(HSROW+2*32); a0=dot4(hv,w2,a0); a1=dot4(hv,w1,a1); a2=dot4(hv,w0,a2); \
      hv=*(const float4*)(HSROW+3*32); a1=dot4(hv,w2,a1); a2=dot4(hv,w1,a2); a3=dot4(hv,w0,a3); \
      hv=*(const float4*)(HSROW+4*32); a2=dot4(hv,w2,a2); a3=dot4(hv,w1,a3); a4=dot4(hv,w0,a4); \
      hv=*(const float4*)(HSROW+5*32); a3=dot4(hv,w2,a3); a4=dot4(hv,w1,a4); a5=dot4(hv,w0,a5); \
      hv=*(const float4*)(HSROW+6*32); a4=dot4(hv,w2,a4); a5=dot4(hv,w1,a5); a6=dot4(hv,w0,a6); \
      hv=*(const float4*)(HSROW+7*32); a5=dot4(hv,w2,a5); a6=dot4(hv,w1,a6); a7=dot4(hv,w0,a7); \
      hv=*(const float4*)(HSROW+8*32); a6=dot4(hv,w2,a6); a7=dot4(hv,w1,a7); \
      hv=*(const float4*)(HSROW+9*32); a7=dot4(hv,w2,a7); }

// ---------------- conv (sliding-window recompute) -> BN partial sums ----------------
__global__ __launch_bounds__(256) void k_convstats(const float* __restrict__ h,
        const float* __restrict__ conv_w, int layer, float* __restrict__ partials)
{
    __shared__ float hs[66*32];      // rows f = t0-1 .. t0+64
    __shared__ float ps[8][32];
    __shared__ float pq[8][32];
    int b=blockIdx.x/NT, t=blockIdx.x%NT, t0=t*TILE, tid=threadIdx.x;
    for (int i4=tid;i4<66*8;i4+=256){
        int r=i4>>3, f=t0-1+r;
        float4 v=make_float4(0.f,0.f,0.f,0.f);
        if (f>=0 && f<FF) v=*(const float4*)(h+(size_t)(b*FF+f)*32+(i4&7)*4);
        *(float4*)&hs[r*32+(i4&7)*4]=v;
    }
    __syncthreads();
    int co=tid&31, rq=tid>>5, rbase=rq*8;
    const float* wl = conv_w + layer*3072 + co;   // [wi][ci][co]
    float a0=0.f,a1=0.f,a2=0.f,a3=0.f,a4=0.f,a5=0.f,a6=0.f,a7=0.f;
    #pragma unroll 1
    for (int c4=0;c4<8;c4++){
        const float* w=wl+c4*128;
        float4 w0=make_float4(w[0],   w[32],  w[64],  w[96]);
        float4 w1=make_float4(w[1024],w[1056],w[1088],w[1120]);
        float4 w2=make_float4(w[2048],w[2080],w[2112],w[2144]);
        const float* hb=&hs[rbase*32+c4*4];
        CONV_C4_BODY(hb)
    }
    float ssum=0.f, ssq=0.f;
    if (t0+rbase+0<FF){ ssum+=a0; ssq+=a0*a0; }
    if (t0+rbase+1<FF){ ssum+=a1; ssq+=a1*a1; }
    if (t0+rbase+2<FF){ ssum+=a2; ssq+=a2*a2; }
    if (t0+rbase+3<FF){ ssum+=a3; ssq+=a3*a3; }
    if (t0+rbase+4<FF){ ssum+=a4; ssq+=a4*a4; }
    if (t0+rbase+5<FF){ ssum+=a5; ssq+=a5*a5; }
    if (t0+rbase+6<FF){ ssum+=a6; ssq+=a6*a6; }
    if (t0+rbase+7<FF){ ssum+=a7; ssq+=a7*a7; }
    ps[rq][co]=ssum; pq[rq][co]=ssq;
    __syncthreads();
    if (tid<32){
        float s=0.f;
        #pragma unroll
        for(int q=0;q<8;q++) s+=ps[q][tid];
        partials[blockIdx.x*64+tid]=s;
    } else if (tid<64){
        int cc=tid-32;
        float s=0.f;
        #pragma unroll
        for(int q=0;q<8;q++) s+=pq[q][cc];
        partials[blockIdx.x*64+tid]=s;
    }
}

// ---------------- reduce partials -> stats[64] (sum | sumsq) ----------------
__global__ __launch_bounds__(256) void k_reduce(const float* __restrict__ partials,
        float* __restrict__ stats)
{
    __shared__ float sm[4][64];
    int tid=threadIdx.x, col=tid&63, rq=tid>>6;
    int r0=blockIdx.x*80;
    float s=0.f;
    for (int k=rq;k<80;k+=4) s += partials[(r0+k)*64+col];
    sm[rq][col]=s;
    __syncthreads();
    if (tid<64){
        float v=sm[0][tid]+sm[1][tid]+sm[2][tid]+sm[3][tid];
        atomicAdd(&stats[tid], v);
    }
}

// LayerNorm-over-32-lanes + guarded store, all in registers/shuffles.
#define LN_STORE(Y,K) { \
    float s=(Y); \
    s+=__shfl_xor(s,1); s+=__shfl_xor(s,2); s+=__shfl_xor(s,4); \
    s+=__shfl_xor(s,8); s+=__shfl_xor(s,16); \
    float m=s*(1.0f/32.0f); \
    float dd=(Y)-m; float v=dd*dd; \
    v+=__shfl_xor(v,1); v+=__shfl_xor(v,2); v+=__shfl_xor(v,4); \
    v+=__shfl_xor(v,8); v+=__shfl_xor(v,16); \
    float rsd=rsqrtf(v*(1.0f/32.0f)+1e-5f); \
    if (t0+rbase+(K)<FF) hn[(size_t)(b*FF+t0+rbase+(K))*32+co]=dd*rsd*lgv+lbv; }

// ---------------- fused layer: conv+qkv one-pass, attn, proj, LN ----------------
__global__ __launch_bounds__(256) void k_layer(const float* __restrict__ h,
        float* __restrict__ hn, const float* __restrict__ stats,
        const float* __restrict__ conv_w, const float* __restrict__ bn_g,
        const float* __restrict__ bn_b, const float* __restrict__ qkv_w,
        const float* __restrict__ proj_w, const float* __restrict__ proj_b,
        const float* __restrict__ ln_g, const float* __restrict__ ln_b, int layer)
{
    __shared__ float hs[67*32];            // rows f = t0-1 .. t0+65
    __shared__ float qs[66*SQ];            // becomes attn output in-place
    __shared__ float ks[66*SQ];
    __shared__ float vs[66*SQ];

    int b=blockIdx.x/NT, t=blockIdx.x%NT, t0=t*TILE, tid=threadIdx.x;
    for (int i4=tid;i4<67*8;i4+=256){
        int r=i4>>3, f=t0-1+r;
        float4 v=make_float4(0.f,0.f,0.f,0.f);
        if (f>=0 && f<FF) v=*(const float4*)(h+(size_t)(b*FF+f)*32+(i4&7)*4);
        *(float4*)&hs[r*32+(i4&7)*4]=v;
    }
    __syncthreads();

    // ---- phase AB: one pass over hs window -> conv a0..a7 AND qkv q/k/v ----
    // qkv row r=rbase+j uses hs[r+1] = window row p=j+1 (p=0..9 is conv window).
    int co=tid&31, rq=tid>>5, rbase=rq*8;
    float y0,y1,y2,y3,y4,y5,y6,y7;
    {
        float mu  = stats[co]*(1.0f/(float)BF);
        float var = stats[32+co]*(1.0f/(float)BF) - mu*mu;
        float rs  = rsqrtf(fmaxf(var,0.f)+1e-5f);
        float g   = bn_g[layer*32+co];
        float scv = g*rs;
        float shv = bn_b[layer*32+co] - mu*g*rs;
        const float* wcl = conv_w + layer*3072 + co;
        const float* wql = qkv_w + layer*3072 + co;
        float a0=0.f,a1=0.f,a2=0.f,a3=0.f,a4=0.f,a5=0.f,a6=0.f,a7=0.f;
        float q0=0.f,q1=0.f,q2=0.f,q3=0.f,q4=0.f,q5=0.f,q6=0.f,q7=0.f;
        float k0=0.f,k1=0.f,k2=0.f,k3=0.f,k4=0.f,k5=0.f,k6=0.f,k7=0.f;
        float v0=0.f,v1=0.f,v2=0.f,v3=0.f,v4=0.f,v5=0.f,v6=0.f,v7=0.f;
        float ek=0.f, ev=0.f;               // tid<64: k,v for row 64+rq
        int edge = (tid<64);
        #pragma unroll 1
        for (int c4=0;c4<8;c4++){
            const float* w=wcl+c4*128;
            float4 w0=make_float4(w[0],   w[32],  w[64],  w[96]);
            float4 w1=make_float4(w[1024],w[1056],w[1088],w[1120]);
            float4 w2=make_float4(w[2048],w[2080],w[2112],w[2144]);
            const float* qw=wql+c4*384;     // ci=c4*4 row, stride 96
            float4 wq=make_float4(qw[0],  qw[96], qw[192],qw[288]);
            float4 wk=make_float4(qw[32], qw[128],qw[224],qw[320]);
            float4 wv=make_float4(qw[64], qw[160],qw[256],qw[352]);
            const float* hb=&hs[rbase*32+c4*4];
            float4 hv;
            hv=*(const float4*)(hb+0*32); a0=dot4(hv,w0,a0);
            hv=*(const float4*)(hb+1*32); a0=dot4(hv,w1,a0); a1=dot4(hv,w0,a1);
                q0=dot4(hv,wq,q0); k0=dot4(hv,wk,k0); v0=dot4(hv,wv,v0);
            hv=*(const float4*)(hb+2*32); a0=dot4(hv,w2,a0); a1=dot4(hv,w1,a1); a2=dot4(hv,w0,a2);
                q1=dot4(hv,wq,q1); k1=dot4(hv,wk,k1); v1=dot4(hv,wv,v1);
            hv=*(const float4*)(hb+3*32); a1=dot4(hv,w2,a1); a2=dot4(hv,w1,a2); a3=dot4(hv,w0,a3);
                q2=dot4(hv,wq,q2); k2=dot4(hv,wk,k2); v2=dot4(hv,wv,v2);
            hv=*(const float4*)(hb+4*32); a2=dot4(hv,w2,a2); a3=dot4(hv,w1,a3); a4=dot4(hv,w0,a4);
                q3=dot4(hv,wq,q3); k3=dot4(hv,wk,k3); v3=dot4(hv,wv,v3);
            hv=*(const float4*)(hb+5*32); a3=dot4(hv,w2,a3); a4=dot4(hv,w1,a4); a5=dot4(hv,w0,a5);
                q4=dot4(hv,wq,q4); k4=dot4(hv,wk,k4); v4=dot4(hv,wv,v4);
            hv=*(const float4*)(hb+6*32); a4=dot4(hv,w2,a4); a5=dot4(hv,w1,a5); a6=dot4(hv,w0,a6);
                q5=dot4(hv,wq,q5); k5=dot4(hv,wk,k5); v5=dot4(hv,wv,v5);
            hv=*(const float4*)(hb+7*32); a5=dot4(hv,w2,a5); a6=dot4(hv,w1,a6); a7=dot4(hv,w0,a7);
                q6=dot4(hv,wq,q6); k6=dot4(hv,wk,k6); v6=dot4(hv,wv,v6);
            hv=*(const float4*)(hb+8*32); a6=dot4(hv,w2,a6); a7=dot4(hv,w1,a7);
                q7=dot4(hv,wq,q7); k7=dot4(hv,wk,k7); v7=dot4(hv,wv,v7);
            hv=*(const float4*)(hb+9*32); a7=dot4(hv,w2,a7);
            if (edge){
                float4 he=*(const float4*)(&hs[(65+rq)*32+c4*4]);
                ek=dot4(he,wk,ek); ev=dot4(he,wv,ev);
            }
        }
        y0=gelu_exact(fmaf(a0,scv,shv));
        y1=gelu_exact(fmaf(a1,scv,shv));
        y2=gelu_exact(fmaf(a2,scv,shv));
        y3=gelu_exact(fmaf(a3,scv,shv));
        y4=gelu_exact(fmaf(a4,scv,shv));
        y5=gelu_exact(fmaf(a5,scv,shv));
        y6=gelu_exact(fmaf(a6,scv,shv));
        y7=gelu_exact(fmaf(a7,scv,shv));
        int rb=rbase*SQ+co;
        qs[rb+0*SQ]=q0; ks[rb+0*SQ]=k0; vs[rb+0*SQ]=v0;
        qs[rb+1*SQ]=q1; ks[rb+1*SQ]=k1; vs[rb+1*SQ]=v1;
        qs[rb+2*SQ]=q2; ks[rb+2*SQ]=k2; vs[rb+2*SQ]=v2;
        qs[rb+3*SQ]=q3; ks[rb+3*SQ]=k3; vs[rb+3*SQ]=v3;
        qs[rb+4*SQ]=q4; ks[rb+4*SQ]=k4; vs[rb+4*SQ]=v4;
        qs[rb+5*SQ]=q5; ks[rb+5*SQ]=k5; vs[rb+5*SQ]=v5;
        qs[rb+6*SQ]=q6; ks[rb+6*SQ]=k6; vs[rb+6*SQ]=v6;
        qs[rb+7*SQ]=q7; ks[rb+7*SQ]=k7; vs[rb+7*SQ]=v7;
        if (edge){ ks[(64+rq)*SQ+co]=ek; vs[(64+rq)*SQ+co]=ev; }
    }
    __syncthreads();

    // ---- phase C: banded attention (qs in-place) ----
    {
        int r=tid>>2, hh=tid&3, f=t0+r;
        if (f<FF){
            int base=hh*8;
            float4 qa=*(const float4*)&qs[r*SQ+base];
            float4 qb=*(const float4*)&qs[r*SQ+base+4];
            float s0, s1=-1e30f, s2=-1e30f;
            s0=dot4(qa,*(const float4*)&ks[r*SQ+base],
               dot4(qb,*(const float4*)&ks[r*SQ+base+4],0.f))*0.35355339059327373f;
            if (f+1<FF)
                s1=dot4(qa,*(const float4*)&ks[(r+1)*SQ+base],
                   dot4(qb,*(const float4*)&ks[(r+1)*SQ+base+4],0.f))*0.35355339059327373f;
            if (f+2<FF)
                s2=dot4(qa,*(const float4*)&ks[(r+2)*SQ+base],
                   dot4(qb,*(const float4*)&ks[(r+2)*SQ+base+4],0.f))*0.35355339059327373f;
            float mx=fmaxf(s0,fmaxf(s1,s2));
            float e0=expf(s0-mx);
            float e1=(f+1<FF)?expf(s1-mx):0.f;
            float e2=(f+2<FF)?expf(s2-mx):0.f;
            float inv=1.0f/(e0+e1+e2);
            float4 va=*(const float4*)&vs[r*SQ+base];
            float4 vb=*(const float4*)&vs[r*SQ+base+4];
            float4 oa=make_float4(e0*va.x,e0*va.y,e0*va.z,e0*va.w);
            float4 ob=make_float4(e0*vb.x,e0*vb.y,e0*vb.z,e0*vb.w);
            if (f+1<FF){
                va=*(const float4*)&vs[(r+1)*SQ+base];
                vb=*(const float4*)&vs[(r+1)*SQ+base+4];
                oa.x=fmaf(e1,va.x,oa.x); oa.y=fmaf(e1,va.y,oa.y);
                oa.z=fmaf(e1,va.z,oa.z); oa.w=fmaf(e1,va.w,oa.w);
                ob.x=fmaf(e1,vb.x,ob.x); ob.y=fmaf(e1,vb.y,ob.y);
                ob.z=fmaf(e1,vb.z,ob.z); ob.w=fmaf(e1,vb.w,ob.w);
            }
            if (f+2<FF){
                va=*(const float4*)&vs[(r+2)*SQ+base];
                vb=*(const float4*)&vs[(r+2)*SQ+base+4];
                oa.x=fmaf(e2,va.x,oa.x); oa.y=fmaf(e2,va.y,oa.y);
                oa.z=fmaf(e2,va.z,oa.z); oa.w=fmaf(e2,va.w,oa.w);
                ob.x=fmaf(e2,vb.x,ob.x); ob.y=fmaf(e2,vb.y,ob.y);
                ob.z=fmaf(e2,vb.z,ob.z); ob.w=fmaf(e2,vb.w,ob.w);
            }
            oa.x*=inv; oa.y*=inv; oa.z*=inv; oa.w*=inv;
            ob.x*=inv; ob.y*=inv; ob.z*=inv; ob.w*=inv;
            *(float4*)&qs[r*SQ+base]=oa;
            *(float4*)&qs[r*SQ+base+4]=ob;
        }
    }
    __syncthreads();

    // ---- phase D: proj + residual into y regs ----
    {
        const float* pwl = proj_w + layer*1024 + co;
        float pbv = proj_b[layer*32+co];
        float d0=pbv,d1=pbv,d2=pbv,d3=pbv,d4=pbv,d5=pbv,d6=pbv,d7=pbv;
        #pragma unroll 1
        for (int c4=0;c4<8;c4++){
            const float* w=pwl+c4*128;
            float4 wv=make_float4(w[0],w[32],w[64],w[96]);
            const float* qb=&qs[rbase*SQ+c4*4];
            d0=dot4(*(const float4*)(qb+0*SQ),wv,d0);
            d1=dot4(*(const float4*)(qb+1*SQ),wv,d1);
            d2=dot4(*(const float4*)(qb+2*SQ),wv,d2);
            d3=dot4(*(const float4*)(qb+3*SQ),wv,d3);
            d4=dot4(*(const float4*)(qb+4*SQ),wv,d4);
            d5=dot4(*(const float4*)(qb+5*SQ),wv,d5);
            d6=dot4(*(const float4*)(qb+6*SQ),wv,d6);
            d7=dot4(*(const float4*)(qb+7*SQ),wv,d7);
        }
        y0+=d0; y1+=d1; y2+=d2; y3+=d3; y4+=d4; y5+=d5; y6+=d6; y7+=d7;
    }

    // ---- phase E: LayerNorm via lane shuffles + fused store ----
    {
        float lgv=ln_g[layer*32+co];
        float lbv=ln_b[layer*32+co];
        LN_STORE(y0,0) LN_STORE(y1,1) LN_STORE(y2,2) LN_STORE(y3,3)
        LN_STORE(y4,4) LN_STORE(y5,5) LN_STORE(y6,6) LN_STORE(y7,7)
    }
}

// ---------------- head: sigmoid(gelu(h@h1+b1)@h2+b2) ----------------
__global__ __launch_bounds__(256) void k_head(const float* __restrict__ h,
        const float* __restrict__ h1_w, const float* __restrict__ h1_b,
        const float* __restrict__ h2_w, const float* __restrict__ h2_b,
        float* __restrict__ out)
{
    __shared__ float hs[256*SQ];
    __shared__ float w1t[16*32];     // transposed h1_w
    int tid=threadIdx.x;
    int r0=blockIdx.x*256;           // BF == 1028*256 exactly
    for (int i4=tid;i4<256*8;i4+=256){
        float4 v=*(const float4*)(h+(size_t)r0*32+i4*4);
        *(float4*)&hs[(i4>>3)*SQ+(i4&7)*4]=v;
    }
    for (int i=tid;i<512;i+=256) w1t[i]=h1_w[(i&31)*16+(i>>5)];
    __syncthreads();
    float4 hv0=*(const float4*)&hs[tid*SQ+ 0];
    float4 hv1=*(const float4*)&hs[tid*SQ+ 4];
    float4 hv2=*(const float4*)&hs[tid*SQ+ 8];
    float4 hv3=*(const float4*)&hs[tid*SQ+12];
    float4 hv4=*(const float4*)&hs[tid*SQ+16];
    float4 hv5=*(const float4*)&hs[tid*SQ+20];
    float4 hv6=*(const float4*)&hs[tid*SQ+24];
    float4 hv7=*(const float4*)&hs[tid*SQ+28];
    float acc2=h2_b[0];
    #pragma unroll
    for (int j=0;j<16;j++){
        const float* wr=&w1t[j*32];
        float aj=h1_b[j];
        aj=dot4(hv0,*(const float4*)(wr+ 0),aj);
        aj=dot4(hv1,*(const float4*)(wr+ 4),aj);
        aj=dot4(hv2,*(const float4*)(wr+ 8),aj);
        aj=dot4(hv3,*(const float4*)(wr+12),aj);
        aj=dot4(hv4,*(const float4*)(wr+16),aj);
        aj=dot4(hv5,*(const float4*)(wr+20),aj);
        aj=dot4(hv6,*(const float4*)(wr+24),aj);
        aj=dot4(hv7,*(const float4*)(wr+28),aj);
        acc2=fmaf(gelu_exact(aj), h2_w[j], acc2);
    }
    out[r0+tid]=1.0f/(1.0f+expf(-acc2));
}

extern "C" void kernel_launch(void* const* d_in, const int* in_sizes, int n_in,
                              void* d_out, int out_size, void* d_ws, size_t ws_size,
                              hipStream_t stream)
{
    const float* x     =(const float*)d_in[0];
    const float* in_w  =(const float*)d_in[1];
    const float* in_b  =(const float*)d_in[2];
    const float* conv_w=(const float*)d_in[3];
    const float* bn_g  =(const float*)d_in[4];
    const float* bn_b  =(const float*)d_in[5];
    const float* qkv_w =(const float*)d_in[6];
    const float* proj_w=(const float*)d_in[7];
    const float* proj_b=(const float*)d_in[8];
    const float* ln_g  =(const float*)d_in[9];
    const float* ln_b  =(const float*)d_in[10];
    const float* h1_w  =(const float*)d_in[11];
    const float* h1_b  =(const float*)d_in[12];
    const float* h2_w  =(const float*)d_in[13];
    const float* h2_b  =(const float*)d_in[14];

    float* bufA     = (float*)d_ws;
    float* bufB     = bufA + (size_t)BF*32;
    float* partials = bufB + (size_t)BF*32;
    float* stats    = partials + (size_t)NBLK*64;

    k_zero<<<1,256,0,stream>>>(stats);
    k_inproj<<<NBLK,256,0,stream>>>(x,in_w,in_b,bufA);
    for (int l=0;l<NLAYER;l++){
        float* cur = (l&1)? bufB : bufA;
        float* nxt = (l&1)? bufA : bufB;
        k_convstats<<<NBLK,256,0,stream>>>(cur, conv_w, l, partials);
        k_reduce<<<64,256,0,stream>>>(partials, stats + l*64);
        k_layer<<<NBLK,256,0,stream>>>(cur, nxt, stats+l*64, conv_w, bn_g, bn_b,
                                       qkv_w, proj_w, proj_b, ln_g, ln_b, l);
    }
    k_head<<<1028,256,0,stream>>>(bufA, h1_w,h1_b,h2_w,h2_b, (float*)d_out);
}

// Round 13
// 599.899 us; speedup vs baseline: 18.3876x; 1.1878x over previous
//
#include <hip/hip_runtime.h>
#include <math.h>

// LightingSpeechShield — B=1024, F=257, C=32; fp32 in/out.
// R11: 729 µs. R12: 713 µs (conv+qkv merge gave only 5% — conv still computed
//      TWICE per layer: once in convstats, once in k_layer).
// R13: k_conv stores raw conv output into `nxt` (same addresses k_layer later
//      overwrites with h_new: read-before-write within block, disjoint across
//      blocks, zero extra ws). k_layer phase AB becomes qkv-only + conv load
//      + BN/gelu: ~35% fewer instructions. __expf in softmax/sigmoid.

#define BB 1024
#define FF 257
#define BF (BB*FF)
#define TILE 64
#define NT 5
#define NBLK (BB*NT)       // 5120
#define NLAYER 4
#define SQ 36              // qs/ks/vs row stride (16B-aligned, bank-rotating)

__device__ __forceinline__ float gelu_exact(float x){
    return 0.5f*x*(1.0f+erff(x*0.70710678118654752f));
}
__device__ __forceinline__ float dot4(float4 a, float4 b, float acc){
    return fmaf(a.x,b.x,fmaf(a.y,b.y,fmaf(a.z,b.z,fmaf(a.w,b.w,acc))));
}

__global__ __launch_bounds__(256) void k_zero(float* __restrict__ stats){
    stats[threadIdx.x]=0.0f;   // 256 = NLAYER*64
}

// ---------------- input projection: h = x(B,F,18) @ in_w(18,32) + in_b ----------------
__global__ __launch_bounds__(256) void k_inproj(const float* __restrict__ x,
        const float* __restrict__ in_w, const float* __restrict__ in_b,
        float* __restrict__ h)
{
    __shared__ float xs[TILE*18];
    int b = blockIdx.x / NT, t = blockIdx.x % NT, t0 = t*TILE;
    int tid = threadIdx.x;
    int nv = min(TILE, FF-t0);
    for (int i=tid;i<nv*18;i+=256) xs[i]=x[(size_t)(b*FF+t0)*18+i];
    __syncthreads();
    int co=tid&31, rq=tid>>5, rbase=rq*8;
    float bias = in_b[co];
    float a0=bias,a1=bias,a2=bias,a3=bias,a4=bias,a5=bias,a6=bias,a7=bias;
    #pragma unroll
    for (int ci=0;ci<18;ci++){
        float w = in_w[ci*32+co];
        a0=fmaf(xs[(rbase+0)*18+ci],w,a0);
        a1=fmaf(xs[(rbase+1)*18+ci],w,a1);
        a2=fmaf(xs[(rbase+2)*18+ci],w,a2);
        a3=fmaf(xs[(rbase+3)*18+ci],w,a3);
        a4=fmaf(xs[(rbase+4)*18+ci],w,a4);
        a5=fmaf(xs[(rbase+5)*18+ci],w,a5);
        a6=fmaf(xs[(rbase+6)*18+ci],w,a6);
        a7=fmaf(xs[(rbase+7)*18+ci],w,a7);
    }
    size_t base=(size_t)(b*FF+t0+rbase)*32+co;
    if (rbase+0<nv) h[base+0*32]=a0;
    if (rbase+1<nv) h[base+1*32]=a1;
    if (rbase+2<nv) h[base+2*32]=a2;
    if (rbase+3<nv) h[base+3*32]=a3;
    if (rbase+4<nv) h[base+4*32]=a4;
    if (rbase+5<nv) h[base+5*32]=a5;
    if (rbase+6<nv) h[base+6*32]=a6;
    if (rbase+7<nv) h[base+7*32]=a7;
}

// sliding-window conv body: 10 broadcast b128 rows, 24 named dot4s.
#define CONV_C4_BODY(HSROW) \
    { float4 hv; \
      hv=*(const float4*)(HSROW+0*32); a0=dot4(hv,w0,a0); \
      hv=*(const float4*)(HSROW+1*32); a0=dot4(hv,w1,a0); a1=dot4(hv,w0,a1); \
      hv=*(const float4*)(HSROW+2*32); a0=dot4(hv,w2,a0); a1=dot4(hv,w1,a1); a2=dot4(hv,w0,a2); \
      hv=*(const float4*)(HSROW+3*32); a1=dot4(hv,w2,a1); a2=dot4(hv,w1,a2); a3=dot4(hv,w0,a3); \
      hv=*(const float4*)(HSROW+4*32); a2=dot4(hv,w2,a2); a3=dot4(hv,w1,a3); a4=dot4(hv,w0,a4); \
      hv=*(const float4*)(HSROW+5*32); a3=dot4(hv,w2,a3); a4=dot4(hv,w1,a4); a5=dot4(hv,w0,a5); \
      hv=*(const float4*)(HSROW+6*32); a4=dot4(hv,w2,a4); a5=dot4(hv,w1,a5); a6=dot4(hv,w0,a6); \
      hv=*(const float4*)(HSROW+7*32); a5=dot4(hv,w2,a5); a6=dot4(hv,w1,a6); a7=dot4(hv,w0,a7); \
      hv=*(const float4*)(HSROW+8*32); a6=dot4(hv,w2,a6); a7=dot4(hv,w1,a7); \
      hv=*(const float4*)(HSROW+9*32); a7=dot4(hv,w2,a7); }

// ---------------- conv -> store raw conv to `c` + BN partial sums ----------------
__global__ __launch_bounds__(256) void k_conv(const float* __restrict__ h,
        const float* __restrict__ conv_w, int layer, float* __restrict__ c,
        float* __restrict__ partials)
{
    __shared__ float hs[66*32];      // rows f = t0-1 .. t0+64
    __shared__ float ps[8][32];
    __shared__ float pq[8][32];
    int b=blockIdx.x/NT, t=blockIdx.x%NT, t0=t*TILE, tid=threadIdx.x;
    for (int i4=tid;i4<66*8;i4+=256){
        int r=i4>>3, f=t0-1+r;
        float4 v=make_float4(0.f,0.f,0.f,0.f);
        if (f>=0 && f<FF) v=*(const float4*)(h+(size_t)(b*FF+f)*32+(i4&7)*4);
        *(float4*)&hs[r*32+(i4&7)*4]=v;
    }
    __syncthreads();
    int co=tid&31, rq=tid>>5, rbase=rq*8;
    const float* wl = conv_w + layer*3072 + co;   // [wi][ci][co]
    float a0=0.f,a1=0.f,a2=0.f,a3=0.f,a4=0.f,a5=0.f,a6=0.f,a7=0.f;
    #pragma unroll 1
    for (int c4=0;c4<8;c4++){
        const float* w=wl+c4*128;
        float4 w0=make_float4(w[0],   w[32],  w[64],  w[96]);
        float4 w1=make_float4(w[1024],w[1056],w[1088],w[1120]);
        float4 w2=make_float4(w[2048],w[2080],w[2112],w[2144]);
        const float* hb=&hs[rbase*32+c4*4];
        CONV_C4_BODY(hb)
    }
    size_t base=(size_t)(b*FF+t0+rbase)*32+co;
    float ssum=0.f, ssq=0.f;
    if (t0+rbase+0<FF){ ssum+=a0; ssq+=a0*a0; c[base+0*32]=a0; }
    if (t0+rbase+1<FF){ ssum+=a1; ssq+=a1*a1; c[base+1*32]=a1; }
    if (t0+rbase+2<FF){ ssum+=a2; ssq+=a2*a2; c[base+2*32]=a2; }
    if (t0+rbase+3<FF){ ssum+=a3; ssq+=a3*a3; c[base+3*32]=a3; }
    if (t0+rbase+4<FF){ ssum+=a4; ssq+=a4*a4; c[base+4*32]=a4; }
    if (t0+rbase+5<FF){ ssum+=a5; ssq+=a5*a5; c[base+5*32]=a5; }
    if (t0+rbase+6<FF){ ssum+=a6; ssq+=a6*a6; c[base+6*32]=a6; }
    if (t0+rbase+7<FF){ ssum+=a7; ssq+=a7*a7; c[base+7*32]=a7; }
    ps[rq][co]=ssum; pq[rq][co]=ssq;
    __syncthreads();
    if (tid<32){
        float s=0.f;
        #pragma unroll
        for(int q=0;q<8;q++) s+=ps[q][tid];
        partials[blockIdx.x*64+tid]=s;
    } else if (tid<64){
        int cc=tid-32;
        float s=0.f;
        #pragma unroll
        for(int q=0;q<8;q++) s+=pq[q][cc];
        partials[blockIdx.x*64+tid]=s;
    }
}

// ---------------- reduce partials -> stats[64] (sum | sumsq) ----------------
__global__ __launch_bounds__(256) void k_reduce(const float* __restrict__ partials,
        float* __restrict__ stats)
{
    __shared__ float sm[4][64];
    int tid=threadIdx.x, col=tid&63, rq=tid>>6;
    int r0=blockIdx.x*80;
    float s=0.f;
    for (int k=rq;k<80;k+=4) s += partials[(r0+k)*64+col];
    sm[rq][col]=s;
    __syncthreads();
    if (tid<64){
        float v=sm[0][tid]+sm[1][tid]+sm[2][tid]+sm[3][tid];
        atomicAdd(&stats[tid], v);
    }
}

// LayerNorm-over-32-lanes + guarded store, all in registers/shuffles.
#define LN_STORE(Y,K) { \
    float s=(Y); \
    s+=__shfl_xor(s,1); s+=__shfl_xor(s,2); s+=__shfl_xor(s,4); \
    s+=__shfl_xor(s,8); s+=__shfl_xor(s,16); \
    float m=s*(1.0f/32.0f); \
    float dd=(Y)-m; float v=dd*dd; \
    v+=__shfl_xor(v,1); v+=__shfl_xor(v,2); v+=__shfl_xor(v,4); \
    v+=__shfl_xor(v,8); v+=__shfl_xor(v,16); \
    float rsd=rsqrtf(v*(1.0f/32.0f)+1e-5f); \
    if (t0+rbase+(K)<FF) hn[(size_t)(b*FF+t0+rbase+(K))*32+co]=dd*rsd*lgv+lbv; }

// ---------------- fused layer: qkv + BN/gelu(conv) + attn + proj + LN ----------------
// cv == hn: conv value (r,co) is read in phase AB strictly before phase E
// overwrites that address; blocks own disjoint row ranges.
__global__ __launch_bounds__(256) void k_layer(const float* __restrict__ h,
        float* __restrict__ hn, const float* __restrict__ cv,
        const float* __restrict__ stats,
        const float* __restrict__ bn_g, const float* __restrict__ bn_b,
        const float* __restrict__ qkv_w, const float* __restrict__ proj_w,
        const float* __restrict__ proj_b, const float* __restrict__ ln_g,
        const float* __restrict__ ln_b, int layer)
{
    __shared__ float hs[66*32];            // rows f = t0 .. t0+65
    __shared__ float qs[66*SQ];            // becomes attn output in-place
    __shared__ float ks[66*SQ];
    __shared__ float vs[66*SQ];

    int b=blockIdx.x/NT, t=blockIdx.x%NT, t0=t*TILE, tid=threadIdx.x;
    for (int i4=tid;i4<66*8;i4+=256){
        int r=i4>>3, f=t0+r;
        float4 v=make_float4(0.f,0.f,0.f,0.f);
        if (f<FF) v=*(const float4*)(h+(size_t)(b*FF+f)*32+(i4&7)*4);
        *(float4*)&hs[r*32+(i4&7)*4]=v;
    }
    __syncthreads();

    int co=tid&31, rq=tid>>5, rbase=rq*8;
    float y0,y1,y2,y3,y4,y5,y6,y7;
    {
        // BN-scale + gelu on stored conv
        float mu  = stats[co]*(1.0f/(float)BF);
        float var = stats[32+co]*(1.0f/(float)BF) - mu*mu;
        float rs  = rsqrtf(fmaxf(var,0.f)+1e-5f);
        float g   = bn_g[layer*32+co];
        float scv = g*rs;
        float shv = bn_b[layer*32+co] - mu*g*rs;
        size_t base=(size_t)(b*FF+t0+rbase)*32+co;
        float c0=(t0+rbase+0<FF)?cv[base+0*32]:0.f;
        float c1=(t0+rbase+1<FF)?cv[base+1*32]:0.f;
        float c2=(t0+rbase+2<FF)?cv[base+2*32]:0.f;
        float c3=(t0+rbase+3<FF)?cv[base+3*32]:0.f;
        float c4v=(t0+rbase+4<FF)?cv[base+4*32]:0.f;
        float c5=(t0+rbase+5<FF)?cv[base+5*32]:0.f;
        float c6=(t0+rbase+6<FF)?cv[base+6*32]:0.f;
        float c7=(t0+rbase+7<FF)?cv[base+7*32]:0.f;
        y0=gelu_exact(fmaf(c0,scv,shv));
        y1=gelu_exact(fmaf(c1,scv,shv));
        y2=gelu_exact(fmaf(c2,scv,shv));
        y3=gelu_exact(fmaf(c3,scv,shv));
        y4=gelu_exact(fmaf(c4v,scv,shv));
        y5=gelu_exact(fmaf(c5,scv,shv));
        y6=gelu_exact(fmaf(c6,scv,shv));
        y7=gelu_exact(fmaf(c7,scv,shv));
    }
    {
        // qkv for rows rbase..rbase+7 (hs row j = f t0+j); edge k/v rows 64,65
        const float* wql = qkv_w + layer*3072 + co;
        float q0=0.f,q1=0.f,q2=0.f,q3=0.f,q4=0.f,q5=0.f,q6=0.f,q7=0.f;
        float k0=0.f,k1=0.f,k2=0.f,k3=0.f,k4=0.f,k5=0.f,k6=0.f,k7=0.f;
        float v0=0.f,v1=0.f,v2=0.f,v3=0.f,v4=0.f,v5=0.f,v6=0.f,v7=0.f;
        float ek=0.f, ev=0.f;               // tid<64: k,v for row 64+rq
        int edge = (tid<64);
        #pragma unroll 1
        for (int c4=0;c4<8;c4++){
            const float* qw=wql+c4*384;     // ci=c4*4, stride 96
            float4 wq=make_float4(qw[0],  qw[96], qw[192],qw[288]);
            float4 wk=make_float4(qw[32], qw[128],qw[224],qw[320]);
            float4 wv=make_float4(qw[64], qw[160],qw[256],qw[352]);
            const float* hb=&hs[rbase*32+c4*4];
            float4 hv;
            hv=*(const float4*)(hb+0*32); q0=dot4(hv,wq,q0); k0=dot4(hv,wk,k0); v0=dot4(hv,wv,v0);
            hv=*(const float4*)(hb+1*32); q1=dot4(hv,wq,q1); k1=dot4(hv,wk,k1); v1=dot4(hv,wv,v1);
            hv=*(const float4*)(hb+2*32); q2=dot4(hv,wq,q2); k2=dot4(hv,wk,k2); v2=dot4(hv,wv,v2);
            hv=*(const float4*)(hb+3*32); q3=dot4(hv,wq,q3); k3=dot4(hv,wk,k3); v3=dot4(hv,wv,v3);
            hv=*(const float4*)(hb+4*32); q4=dot4(hv,wq,q4); k4=dot4(hv,wk,k4); v4=dot4(hv,wv,v4);
            hv=*(const float4*)(hb+5*32); q5=dot4(hv,wq,q5); k5=dot4(hv,wk,k5); v5=dot4(hv,wv,v5);
            hv=*(const float4*)(hb+6*32); q6=dot4(hv,wq,q6); k6=dot4(hv,wk,k6); v6=dot4(hv,wv,v6);
            hv=*(const float4*)(hb+7*32); q7=dot4(hv,wq,q7); k7=dot4(hv,wk,k7); v7=dot4(hv,wv,v7);
            if (edge){
                float4 he=*(const float4*)(&hs[(64+rq)*32+c4*4]);
                ek=dot4(he,wk,ek); ev=dot4(he,wv,ev);
            }
        }
        int rb=rbase*SQ+co;
        qs[rb+0*SQ]=q0; ks[rb+0*SQ]=k0; vs[rb+0*SQ]=v0;
        qs[rb+1*SQ]=q1; ks[rb+1*SQ]=k1; vs[rb+1*SQ]=v1;
        qs[rb+2*SQ]=q2; ks[rb+2*SQ]=k2; vs[rb+2*SQ]=v2;
        qs[rb+3*SQ]=q3; ks[rb+3*SQ]=k3; vs[rb+3*SQ]=v3;
        qs[rb+4*SQ]=q4; ks[rb+4*SQ]=k4; vs[rb+4*SQ]=v4;
        qs[rb+5*SQ]=q5; ks[rb+5*SQ]=k5; vs[rb+5*SQ]=v5;
        qs[rb+6*SQ]=q6; ks[rb+6*SQ]=k6; vs[rb+6*SQ]=v6;
        qs[rb+7*SQ]=q7; ks[rb+7*SQ]=k7; vs[rb+7*SQ]=v7;
        if (edge){ ks[(64+rq)*SQ+co]=ek; vs[(64+rq)*SQ+co]=ev; }
    }
    __syncthreads();

    // ---- phase C: banded attention (qs in-place) ----
    {
        int r=tid>>2, hh=tid&3, f=t0+r;
        if (f<FF){
            int base=hh*8;
            float4 qa=*(const float4*)&qs[r*SQ+base];
            float4 qb=*(const float4*)&qs[r*SQ+base+4];
            float s0, s1=-1e30f, s2=-1e30f;
            s0=dot4(qa,*(const float4*)&ks[r*SQ+base],
               dot4(qb,*(const float4*)&ks[r*SQ+base+4],0.f))*0.35355339059327373f;
            if (f+1<FF)
                s1=dot4(qa,*(const float4*)&ks[(r+1)*SQ+base],
                   dot4(qb,*(const float4*)&ks[(r+1)*SQ+base+4],0.f))*0.35355339059327373f;
            if (f+2<FF)
                s2=dot4(qa,*(const float4*)&ks[(r+2)*SQ+base],
                   dot4(qb,*(const float4*)&ks[(r+2)*SQ+base+4],0.f))*0.35355339059327373f;
            float mx=fmaxf(s0,fmaxf(s1,s2));
            float e0=__expf(s0-mx);
            float e1=(f+1<FF)?__expf(s1-mx):0.f;
            float e2=(f+2<FF)?__expf(s2-mx):0.f;
            float inv=1.0f/(e0+e1+e2);
            float4 va=*(const float4*)&vs[r*SQ+base];
            float4 vb=*(const float4*)&vs[r*SQ+base+4];
            float4 oa=make_float4(e0*va.x,e0*va.y,e0*va.z,e0*va.w);
            float4 ob=make_float4(e0*vb.x,e0*vb.y,e0*vb.z,e0*vb.w);
            if (f+1<FF){
                va=*(const float4*)&vs[(r+1)*SQ+base];
                vb=*(const float4*)&vs[(r+1)*SQ+base+4];
                oa.x=fmaf(e1,va.x,oa.x); oa.y=fmaf(e1,va.y,oa.y);
                oa.z=fmaf(e1,va.z,oa.z); oa.w=fmaf(e1,va.w,oa.w);
                ob.x=fmaf(e1,vb.x,ob.x); ob.y=fmaf(e1,vb.y,ob.y);
                ob.z=fmaf(e1,vb.z,ob.z); ob.w=fmaf(e1,vb.w,ob.w);
            }
            if (f+2<FF){
                va=*(const float4*)&vs[(r+2)*SQ+base];
                vb=*(const float4*)&vs[(r+2)*SQ+base+4];
                oa.x=fmaf(e2,va.x,oa.x); oa.y=fmaf(e2,va.y,oa.y);
                oa.z=fmaf(e2,va.z,oa.z); oa.w=fmaf(e2,va.w,oa.w);
                ob.x=fmaf(e2,vb.x,ob.x); ob.y=fmaf(e2,vb.y,ob.y);
                ob.z=fmaf(e2,vb.z,ob.z); ob.w=fmaf(e2,vb.w,ob.w);
            }
            oa.x*=inv; oa.y*=inv; oa.z*=inv; oa.w*=inv;
            ob.x*=inv; ob.y*=inv; ob.z*=inv; ob.w*=inv;
            *(float4*)&qs[r*SQ+base]=oa;
            *(float4*)&qs[r*SQ+base+4]=ob;
        }
    }
    __syncthreads();

    // ---- phase D: proj + residual into y regs ----
    {
        const float* pwl = proj_w + layer*1024 + co;
        float pbv = proj_b[layer*32+co];
        float d0=pbv,d1=pbv,d2=pbv,d3=pbv,d4=pbv,d5=pbv,d6=pbv,d7=pbv;
        #pragma unroll 1
        for (int c4=0;c4<8;c4++){
            const float* w=pwl+c4*128;
            float4 wv=make_float4(w[0],w[32],w[64],w[96]);
            const float* qb=&qs[rbase*SQ+c4*4];
            d0=dot4(*(const float4*)(qb+0*SQ),wv,d0);
            d1=dot4(*(const float4*)(qb+1*SQ),wv,d1);
            d2=dot4(*(const float4*)(qb+2*SQ),wv,d2);
            d3=dot4(*(const float4*)(qb+3*SQ),wv,d3);
            d4=dot4(*(const float4*)(qb+4*SQ),wv,d4);
            d5=dot4(*(const float4*)(qb+5*SQ),wv,d5);
            d6=dot4(*(const float4*)(qb+6*SQ),wv,d6);
            d7=dot4(*(const float4*)(qb+7*SQ),wv,d7);
        }
        y0+=d0; y1+=d1; y2+=d2; y3+=d3; y4+=d4; y5+=d5; y6+=d6; y7+=d7;
    }

    // ---- phase E: LayerNorm via lane shuffles + fused store ----
    {
        float lgv=ln_g[layer*32+co];
        float lbv=ln_b[layer*32+co];
        LN_STORE(y0,0) LN_STORE(y1,1) LN_STORE(y2,2) LN_STORE(y3,3)
        LN_STORE(y4,4) LN_STORE(y5,5) LN_STORE(y6,6) LN_STORE(y7,7)
    }
}

// ---------------- head: sigmoid(gelu(h@h1+b1)@h2+b2) ----------------
__global__ __launch_bounds__(256) void k_head(const float* __restrict__ h,
        const float* __restrict__ h1_w, const float* __restrict__ h1_b,
        const float* __restrict__ h2_w, const float* __restrict__ h2_b,
        float* __restrict__ out)
{
    __shared__ float hs[256*SQ];
    __shared__ float w1t[16*32];     // transposed h1_w
    int tid=threadIdx.x;
    int r0=blockIdx.x*256;           // BF == 1028*256 exactly
    for (int i4=tid;i4<256*8;i4+=256){
        float4 v=*(const float4*)(h+(size_t)r0*32+i4*4);
        *(float4*)&hs[(i4>>3)*SQ+(i4&7)*4]=v;
    }
    for (int i=tid;i<512;i+=256) w1t[i]=h1_w[(i&31)*16+(i>>5)];
    __syncthreads();
    float4 hv0=*(const float4*)&hs[tid*SQ+ 0];
    float4 hv1=*(const float4*)&hs[tid*SQ+ 4];
    float4 hv2=*(const float4*)&hs[tid*SQ+ 8];
    float4 hv3=*(const float4*)&hs[tid*SQ+12];
    float4 hv4=*(const float4*)&hs[tid*SQ+16];
    float4 hv5=*(const float4*)&hs[tid*SQ+20];
    float4 hv6=*(const float4*)&hs[tid*SQ+24];
    float4 hv7=*(const float4*)&hs[tid*SQ+28];
    float acc2=h2_b[0];
    #pragma unroll
    for (int j=0;j<16;j++){
        const float* wr=&w1t[j*32];
        float aj=h1_b[j];
        aj=dot4(hv0,*(const float4*)(wr+ 0),aj);
        aj=dot4(hv1,*(const float4*)(wr+ 4),aj);
        aj=dot4(hv2,*(const float4*)(wr+ 8),aj);
        aj=dot4(hv3,*(const float4*)(wr+12),aj);
        aj=dot4(hv4,*(const float4*)(wr+16),aj);
        aj=dot4(hv5,*(const float4*)(wr+20),aj);
        aj=dot4(hv6,*(const float4*)(wr+24),aj);
        aj=dot4(hv7,*(const float4*)(wr+28),aj);
        acc2=fmaf(gelu_exact(aj), h2_w[j], acc2);
    }
    out[r0+tid]=1.0f/(1.0f+__expf(-acc2));
}

extern "C" void kernel_launch(void* const* d_in, const int* in_sizes, int n_in,
                              void* d_out, int out_size, void* d_ws, size_t ws_size,
                              hipStream_t stream)
{
    const float* x     =(const float*)d_in[0];
    const float* in_w  =(const float*)d_in[1];
    const float* in_b  =(const float*)d_in[2];
    const float* conv_w=(const float*)d_in[3];
    const float* bn_g  =(const float*)d_in[4];
    const float* bn_b  =(const float*)d_in[5];
    const float* qkv_w =(const float*)d_in[6];
    const float* proj_w=(const float*)d_in[7];
    const float* proj_b=(const float*)d_in[8];
    const float* ln_g  =(const float*)d_in[9];
    const float* ln_b  =(const float*)d_in[10];
    const float* h1_w  =(const float*)d_in[11];
    const float* h1_b  =(const float*)d_in[12];
    const float* h2_w  =(const float*)d_in[13];
    const float* h2_b  =(const float*)d_in[14];

    float* bufA     = (float*)d_ws;
    float* bufB     = bufA + (size_t)BF*32;
    float* partials = bufB + (size_t)BF*32;
    float* stats    = partials + (size_t)NBLK*64;

    k_zero<<<1,256,0,stream>>>(stats);
    k_inproj<<<NBLK,256,0,stream>>>(x,in_w,in_b,bufA);
    for (int l=0;l<NLAYER;l++){
        float* cur = (l&1)? bufB : bufA;
        float* nxt = (l&1)? bufA : bufB;
        k_conv<<<NBLK,256,0,stream>>>(cur, conv_w, l, nxt, partials);
        k_reduce<<<64,256,0,stream>>>(partials, stats + l*64);
        k_layer<<<NBLK,256,0,stream>>>(cur, nxt, nxt, stats+l*64, bn_g, bn_b,
                                       qkv_w, proj_w, proj_b, ln_g, ln_b, l);
    }
    k_head<<<1028,256,0,stream>>>(bufA, h1_w,h1_b,h2_w,h2_b, (float*)d_out);
}